// Round 1
// baseline (611.944 us; speedup 1.0000x reference)
//
#include <hip/hip_runtime.h>
#include <hip/hip_bf16.h>

#define N_NODES 20000
#define E_ORIG  160000
#define E_TOT   180000
#define HEADS   8
#define HID     256
#define F1      2048   // HEADS*HID
#define NEG     0.2f
#define MAXDEG  256

typedef __attribute__((ext_vector_type(8))) short  short8;
typedef __attribute__((ext_vector_type(4))) float  float4_;

__device__ inline float bf2f(ushort u){ union{unsigned u32; float f;} v; v.u32=((unsigned)u)<<16; return v.f; }
__device__ inline ushort f2bf(float f){
  union{float f; unsigned u;} v; v.f=f;
  unsigned lsb=(v.u>>16)&1u; v.u += 0x7fffu + lsb; return (ushort)(v.u>>16);
}

// ---------------- CSR build ----------------
__global__ void k_count(const int* __restrict__ ei, int* __restrict__ deg){
  int e = blockIdx.x*256 + threadIdx.x;
  if (e >= E_TOT) return;
  int d = (e < E_ORIG) ? ei[E_ORIG + e] : (e - E_ORIG);
  atomicAdd(&deg[d], 1);
}

__global__ __launch_bounds__(1024) void k_scan(const int* __restrict__ deg,
                                               int* __restrict__ rowptr,
                                               int* __restrict__ cursor){
  __shared__ int s[1024];
  __shared__ int base;
  int tid = threadIdx.x;
  if (tid==0) base = 0;
  __syncthreads();
  for (int start=0; start<N_NODES; start+=1024){
    int i = start + tid;
    int v = (i<N_NODES) ? deg[i] : 0;
    s[tid] = v; __syncthreads();
    for (int off=1; off<1024; off<<=1){
      int t = (tid>=off) ? s[tid-off] : 0;
      __syncthreads();
      s[tid] += t;
      __syncthreads();
    }
    if (i<N_NODES){ int ex = base + s[tid] - v; rowptr[i]=ex; cursor[i]=ex; }
    __syncthreads();
    if (tid==0) base += s[1023];
    __syncthreads();
  }
  if (tid==0) rowptr[N_NODES] = base;
}

__global__ void k_scatter(const int* __restrict__ ei, int* __restrict__ cursor,
                          int* __restrict__ csrc){
  int e = blockIdx.x*256 + threadIdx.x;
  if (e >= E_TOT) return;
  int s, d;
  if (e < E_ORIG){ s = ei[e]; d = ei[E_ORIG + e]; }
  else           { s = d = e - E_ORIG; }
  int pos = atomicAdd(&cursor[d], 1);
  csrc[pos] = s;
}

// ---------------- conv1 GEMM + attention dots ----------------
// h1T layout: [node][channel c][head k] as bf16, so a (node,c) pair is 8 bf16 = 16B.
__global__ __launch_bounds__(256) void k_gemm1(const float* __restrict__ x,
    const float* __restrict__ W1, const float* __restrict__ att_s, const float* __restrict__ att_d,
    ushort* __restrict__ h1T, float* __restrict__ a_src1, float* __restrict__ a_dst1){
  int n = blockIdx.x, tid = threadIdx.x;
  float xv[7];
#pragma unroll
  for (int i=0;i<7;i++) xv[i] = x[n*7+i];
  float h[8], ps[8], pd[8];
#pragma unroll
  for (int k=0;k<8;k++){
    int o = (k<<8) + tid;            // flat col = k*256 + c, c = tid
    float acc = 0.f;
#pragma unroll
    for (int i=0;i<7;i++) acc += xv[i]*W1[i*F1 + o];
    h[k] = acc;
    ps[k] = acc*att_s[o];
    pd[k] = acc*att_d[o];
  }
  short8 pk;
#pragma unroll
  for (int k=0;k<8;k++) pk[k] = (short)f2bf(h[k]);
  *(short8*)(h1T + (size_t)n*F1 + tid*8) = pk;

  __shared__ float rs[4][8], rd[4][8];
  int lane = tid&63, wv = tid>>6;
#pragma unroll
  for (int k=0;k<8;k++){
    float a = ps[k], b = pd[k];
    for (int off=32; off; off>>=1){ a += __shfl_down(a,off); b += __shfl_down(b,off); }
    if (lane==0){ rs[wv][k]=a; rd[wv][k]=b; }
  }
  __syncthreads();
  if (tid<8)       a_src1[n*8+tid]   = rs[0][tid]+rs[1][tid]+rs[2][tid]+rs[3][tid];
  else if (tid<16){ int k=tid-8; a_dst1[n*8+k] = rd[0][k]+rd[1][k]+rd[2][k]+rd[3][k]; }
}

__global__ void k_wconv(const float* __restrict__ W2, ushort* __restrict__ W2b, int n){
  int i = blockIdx.x*256 + threadIdx.x;
  if (i<n) W2b[i] = f2bf(W2[i]);
}

// ---------------- conv1 aggregation: softmax + weighted sum + bias + ELU ----------------
__global__ __launch_bounds__(256) void k_agg1(const int* __restrict__ rowptr, const int* __restrict__ csrc,
    const float* __restrict__ a_src1, const float* __restrict__ a_dst1, const ushort* __restrict__ h1T,
    const float* __restrict__ b1, ushort* __restrict__ x2){
  int n = blockIdx.x, tid = threadIdx.x;
  __shared__ int   ssrc[MAXDEG];
  __shared__ float sw[MAXDEG][8];
  __shared__ float sad[8];
  int base = rowptr[n];
  int deg  = rowptr[n+1] - base;
  if (deg > MAXDEG) deg = MAXDEG;
  if (tid<8) sad[tid] = a_dst1[n*8+tid];
  for (int j=tid; j<deg; j+=256) ssrc[j] = csrc[base+j];
  __syncthreads();
  for (int idx=tid; idx<deg*8; idx+=256){
    int j = idx>>3, k = idx&7;
    float a = a_src1[ssrc[j]*8+k] + sad[k];
    sw[j][k] = (a>0.f) ? a : NEG*a;
  }
  __syncthreads();
  if (tid<8){
    int k = tid;
    float m = -1e30f;
    for (int j=0;j<deg;j++) m = fmaxf(m, sw[j][k]);
    float s = 0.f;
    for (int j=0;j<deg;j++){ float e = __expf(sw[j][k]-m); sw[j][k]=e; s+=e; }
    float inv = 1.f/(s + 1e-16f);
    for (int j=0;j<deg;j++) sw[j][k] *= inv;
  }
  __syncthreads();
  float acc[8] = {0,0,0,0,0,0,0,0};
  for (int j=0;j<deg;j++){
    short8 hv = *(const short8*)(h1T + (size_t)ssrc[j]*F1 + tid*8);
    float w0=sw[j][0], w1=sw[j][1], w2=sw[j][2], w3=sw[j][3];
    float w4=sw[j][4], w5=sw[j][5], w6=sw[j][6], w7=sw[j][7];
    acc[0] += w0*bf2f((ushort)hv[0]); acc[1] += w1*bf2f((ushort)hv[1]);
    acc[2] += w2*bf2f((ushort)hv[2]); acc[3] += w3*bf2f((ushort)hv[3]);
    acc[4] += w4*bf2f((ushort)hv[4]); acc[5] += w5*bf2f((ushort)hv[5]);
    acc[6] += w6*bf2f((ushort)hv[6]); acc[7] += w7*bf2f((ushort)hv[7]);
  }
#pragma unroll
  for (int k=0;k<8;k++){
    int col = (k<<8) + tid;
    float v = acc[k] + b1[col];
    v = (v>0.f) ? v : (__expf(v)-1.f);   // ELU between the two convs
    x2[(size_t)n*F1 + col] = f2bf(v);
  }
}

// ---------------- conv2 GEMM (bf16 in, fp32 acc, vector ALU) ----------------
#define BM 128
#define BN 64
#define BK 32
__global__ __launch_bounds__(256) void k_gemm2(const ushort* __restrict__ A,
    const ushort* __restrict__ B, float* __restrict__ C){
  __shared__ float As[BK][BM];      // transposed: [kk][row]
  __shared__ float Bs[BK][BN+4];
  int tid = threadIdx.x;
  int m0 = blockIdx.x*BM, n0 = blockIdx.y*BN;
  int tx = tid&15, ty = tid>>4;
  float acc[8][4] = {};
  int arow = tid>>1, ahalf = tid&1;
  int brow = tid&31, bcol8 = (tid>>5)*8;
  int garow = m0 + arow; if (garow >= N_NODES) garow = N_NODES-1;
  for (int k0=0; k0<F1; k0+=BK){
    short8 av0 = *(const short8*)(A + (size_t)garow*F1 + k0 + ahalf*16);
    short8 av1 = *(const short8*)(A + (size_t)garow*F1 + k0 + ahalf*16 + 8);
    short8 bv  = *(const short8*)(B + (size_t)(k0+brow)*256 + n0 + bcol8);
    __syncthreads();
#pragma unroll
    for (int i=0;i<8;i++) As[ahalf*16+i][arow]   = bf2f((ushort)av0[i]);
#pragma unroll
    for (int i=0;i<8;i++) As[ahalf*16+8+i][arow] = bf2f((ushort)av1[i]);
#pragma unroll
    for (int i=0;i<8;i++) Bs[brow][bcol8+i]      = bf2f((ushort)bv[i]);
    __syncthreads();
#pragma unroll
    for (int kk=0; kk<BK; kk++){
      float4_ a0 = *(float4_*)&As[kk][ty*8];
      float4_ a1 = *(float4_*)&As[kk][ty*8+4];
      float4_ b  = *(float4_*)&Bs[kk][tx*4];
#pragma unroll
      for (int r=0;r<4;r++){
#pragma unroll
        for (int c=0;c<4;c++){
          acc[r][c]   += a0[r]*b[c];
          acc[r+4][c] += a1[r]*b[c];
        }
      }
    }
  }
#pragma unroll
  for (int r=0;r<8;r++){
    int row = m0 + ty*8 + r;
    if (row < N_NODES){
      float4_ v; v[0]=acc[r][0]; v[1]=acc[r][1]; v[2]=acc[r][2]; v[3]=acc[r][3];
      *(float4_*)(C + (size_t)row*256 + n0 + tx*4) = v;
    }
  }
}

// ---------------- conv2 attention dots ----------------
__global__ __launch_bounds__(256) void k_dots2(const float* __restrict__ h2,
    const float* __restrict__ as2, const float* __restrict__ ad2,
    float* __restrict__ a_src2, float* __restrict__ a_dst2){
  int n = blockIdx.x, tid = threadIdx.x;
  float h = h2[(size_t)n*256 + tid];
  float a = h*as2[tid], b = h*ad2[tid];
  for (int off=32; off; off>>=1){ a += __shfl_down(a,off); b += __shfl_down(b,off); }
  __shared__ float ra[4], rb[4];
  int lane = tid&63, wv = tid>>6;
  if (!lane){ ra[wv]=a; rb[wv]=b; }
  __syncthreads();
  if (tid==0) a_src2[n] = ra[0]+ra[1]+ra[2]+ra[3];
  if (tid==1) a_dst2[n] = rb[0]+rb[1]+rb[2]+rb[3];
}

// ---------------- conv2 aggregation → output ----------------
__global__ __launch_bounds__(256) void k_agg2(const int* __restrict__ rowptr, const int* __restrict__ csrc,
    const float* __restrict__ a_src2, const float* __restrict__ a_dst2, const float* __restrict__ h2,
    const float* __restrict__ b2, float* __restrict__ out){
  int n = blockIdx.x, tid = threadIdx.x;
  __shared__ int   ssrc[MAXDEG];
  __shared__ float sw[MAXDEG];
  int base = rowptr[n];
  int deg  = rowptr[n+1] - base;
  if (deg > MAXDEG) deg = MAXDEG;
  for (int j=tid; j<deg; j+=256) ssrc[j] = csrc[base+j];
  __syncthreads();
  if (tid < 64){
    float ad = a_dst2[n];
    float m = -1e30f;
    for (int j=tid; j<deg; j+=64){
      float a = a_src2[ssrc[j]] + ad;
      a = (a>0.f) ? a : NEG*a;
      sw[j] = a; m = fmaxf(m, a);
    }
    for (int off=32; off; off>>=1) m = fmaxf(m, __shfl_xor(m,off));
    float s = 0.f;
    for (int j=tid; j<deg; j+=64){ float e = __expf(sw[j]-m); sw[j]=e; s+=e; }
    for (int off=32; off; off>>=1) s += __shfl_xor(s,off);
    float inv = 1.f/(s + 1e-16f);
    for (int j=tid; j<deg; j+=64) sw[j] *= inv;
  }
  __syncthreads();
  float acc = 0.f;
  for (int j=0;j<deg;j++) acc += sw[j]*h2[(size_t)ssrc[j]*256 + tid];
  out[(size_t)n*256 + tid] = acc + b2[tid];
}

extern "C" void kernel_launch(void* const* d_in, const int* in_sizes, int n_in,
                              void* d_out, int out_size, void* d_ws, size_t ws_size,
                              hipStream_t stream){
  const float* x      = (const float*)d_in[0];
  const int*   ei     = (const int*)  d_in[1];
  const float* W1     = (const float*)d_in[2];
  const float* att_s1 = (const float*)d_in[3];
  const float* att_d1 = (const float*)d_in[4];
  const float* b1     = (const float*)d_in[5];
  const float* W2     = (const float*)d_in[6];
  const float* att_s2 = (const float*)d_in[7];
  const float* att_d2 = (const float*)d_in[8];
  const float* b2     = (const float*)d_in[9];
  float* out = (float*)d_out;

  char* p = (char*)d_ws;
  auto alloc = [&](size_t bytes)->char*{ char* r = p; p += (bytes + 255) & ~(size_t)255; return r; };
  ushort* h1T   = (ushort*)alloc((size_t)N_NODES*F1*2);
  ushort* x2    = (ushort*)alloc((size_t)N_NODES*F1*2);
  ushort* W2b   = (ushort*)alloc((size_t)F1*256*2);
  float*  h2    = (float*) alloc((size_t)N_NODES*256*4);
  float*  a_src1= (float*) alloc((size_t)N_NODES*8*4);
  float*  a_dst1= (float*) alloc((size_t)N_NODES*8*4);
  float*  a_src2= (float*) alloc((size_t)N_NODES*4);
  float*  a_dst2= (float*) alloc((size_t)N_NODES*4);
  int*    deg   = (int*)   alloc((size_t)N_NODES*4);
  int*    rowptr= (int*)   alloc((size_t)(N_NODES+1)*4);
  int*    cursor= (int*)   alloc((size_t)N_NODES*4);
  int*    csrc  = (int*)   alloc((size_t)E_TOT*4);

  hipMemsetAsync(deg, 0, (size_t)N_NODES*4, stream);
  k_count  <<<(E_TOT+255)/256, 256, 0, stream>>>(ei, deg);
  k_scan   <<<1, 1024, 0, stream>>>(deg, rowptr, cursor);
  k_scatter<<<(E_TOT+255)/256, 256, 0, stream>>>(ei, cursor, csrc);
  k_gemm1  <<<N_NODES, 256, 0, stream>>>(x, W1, att_s1, att_d1, h1T, a_src1, a_dst1);
  k_wconv  <<<(F1*256+255)/256, 256, 0, stream>>>(W2, W2b, F1*256);
  k_agg1   <<<N_NODES, 256, 0, stream>>>(rowptr, csrc, a_src1, a_dst1, h1T, b1, x2);
  dim3 g2((N_NODES+BM-1)/BM, 256/BN);
  k_gemm2  <<<g2, 256, 0, stream>>>(x2, W2b, h2);
  k_dots2  <<<N_NODES, 256, 0, stream>>>(h2, att_s2, att_d2, a_src2, a_dst2);
  k_agg2   <<<N_NODES, 256, 0, stream>>>(rowptr, csrc, a_src2, a_dst2, h2, b2, out);
}

// Round 2
// 382.239 us; speedup vs baseline: 1.6009x; 1.6009x over previous
//
#include <hip/hip_runtime.h>
#include <hip/hip_bf16.h>

#define N_NODES 20000
#define E_ORIG  160000
#define E_TOT   180000
#define HEADS   8
#define HID     256
#define F1      2048   // HEADS*HID
#define NEG     0.2f
#define MAXDEG  256

typedef __attribute__((ext_vector_type(8))) short  short8;
typedef __attribute__((ext_vector_type(4))) float  f32x4;

__device__ inline float bf2f(ushort u){ union{unsigned u32; float f;} v; v.u32=((unsigned)u)<<16; return v.f; }
__device__ inline ushort f2bf(float f){
  union{float f; unsigned u;} v; v.f=f;
  unsigned lsb=(v.u>>16)&1u; v.u += 0x7fffu + lsb; return (ushort)(v.u>>16);
}

__device__ inline void gload16(const ushort* g, ushort* s){
  __builtin_amdgcn_global_load_lds((const __attribute__((address_space(1))) unsigned int*)g,
                                   (__attribute__((address_space(3))) unsigned int*)s, 16, 0, 0);
}

// ---------------- CSR build ----------------
__global__ void k_count(const int* __restrict__ ei, int* __restrict__ deg){
  int e = blockIdx.x*256 + threadIdx.x;
  if (e >= E_TOT) return;
  int d = (e < E_ORIG) ? ei[E_ORIG + e] : (e - E_ORIG);
  atomicAdd(&deg[d], 1);
}

__global__ __launch_bounds__(1024) void k_scan(const int* __restrict__ deg,
                                               int* __restrict__ rowptr,
                                               int* __restrict__ cursor){
  __shared__ int s[1024];
  __shared__ int base;
  int tid = threadIdx.x;
  if (tid==0) base = 0;
  __syncthreads();
  for (int start=0; start<N_NODES; start+=1024){
    int i = start + tid;
    int v = (i<N_NODES) ? deg[i] : 0;
    s[tid] = v; __syncthreads();
    for (int off=1; off<1024; off<<=1){
      int t = (tid>=off) ? s[tid-off] : 0;
      __syncthreads();
      s[tid] += t;
      __syncthreads();
    }
    if (i<N_NODES){ int ex = base + s[tid] - v; rowptr[i]=ex; cursor[i]=ex; }
    __syncthreads();
    if (tid==0) base += s[1023];
    __syncthreads();
  }
  if (tid==0) rowptr[N_NODES] = base;
}

__global__ void k_scatter(const int* __restrict__ ei, int* __restrict__ cursor,
                          int* __restrict__ csrc){
  int e = blockIdx.x*256 + threadIdx.x;
  if (e >= E_TOT) return;
  int s, d;
  if (e < E_ORIG){ s = ei[e]; d = ei[E_ORIG + e]; }
  else           { s = d = e - E_ORIG; }
  int pos = atomicAdd(&cursor[d], 1);
  csrc[pos] = s;
}

// ---------------- conv1 GEMM + attention dots ----------------
__global__ __launch_bounds__(256) void k_gemm1(const float* __restrict__ x,
    const float* __restrict__ W1, const float* __restrict__ att_s, const float* __restrict__ att_d,
    ushort* __restrict__ h1T, float* __restrict__ a_src1, float* __restrict__ a_dst1){
  int n = blockIdx.x, tid = threadIdx.x;
  float xv[7];
#pragma unroll
  for (int i=0;i<7;i++) xv[i] = x[n*7+i];
  float h[8], ps[8], pd[8];
#pragma unroll
  for (int k=0;k<8;k++){
    int o = (k<<8) + tid;
    float acc = 0.f;
#pragma unroll
    for (int i=0;i<7;i++) acc += xv[i]*W1[i*F1 + o];
    h[k] = acc;
    ps[k] = acc*att_s[o];
    pd[k] = acc*att_d[o];
  }
  short8 pk;
#pragma unroll
  for (int k=0;k<8;k++) pk[k] = (short)f2bf(h[k]);
  *(short8*)(h1T + (size_t)n*F1 + tid*8) = pk;

  __shared__ float rs[4][8], rd[4][8];
  int lane = tid&63, wv = tid>>6;
#pragma unroll
  for (int k=0;k<8;k++){
    float a = ps[k], b = pd[k];
    for (int off=32; off; off>>=1){ a += __shfl_down(a,off); b += __shfl_down(b,off); }
    if (lane==0){ rs[wv][k]=a; rd[wv][k]=b; }
  }
  __syncthreads();
  if (tid<8)       a_src1[n*8+tid]   = rs[0][tid]+rs[1][tid]+rs[2][tid]+rs[3][tid];
  else if (tid<16){ int k=tid-8; a_dst1[n*8+k] = rd[0][k]+rd[1][k]+rd[2][k]+rd[3][k]; }
}

// ---------------- W2 -> bf16 transposed [256][2048] ----------------
__global__ __launch_bounds__(256) void k_wT(const float* __restrict__ W2, ushort* __restrict__ BT){
  __shared__ ushort sh[256][65];
  int k0 = blockIdx.x*64, t = threadIdx.x;
  for (int kk=0; kk<64; kk++) sh[t][kk] = f2bf(W2[(size_t)(k0+kk)*256 + t]);
  __syncthreads();
#pragma unroll
  for (int c8=0; c8<8; c8++){
    short8 v;
#pragma unroll
    for (int j=0;j<8;j++) v[j] = (short)sh[t][c8*8+j];
    *(short8*)&BT[(size_t)t*F1 + k0 + c8*8] = v;
  }
}

// ---------------- conv1 aggregation: softmax + weighted sum + bias + ELU ----------------
__global__ __launch_bounds__(256) void k_agg1(const int* __restrict__ rowptr, const int* __restrict__ csrc,
    const float* __restrict__ a_src1, const float* __restrict__ a_dst1, const ushort* __restrict__ h1T,
    const float* __restrict__ b1, ushort* __restrict__ x2){
  int n = blockIdx.x, tid = threadIdx.x;
  __shared__ int   ssrc[MAXDEG];
  __shared__ float sw[MAXDEG][8];
  __shared__ float sad[8];
  int base = rowptr[n];
  int deg  = rowptr[n+1] - base;
  if (deg > MAXDEG) deg = MAXDEG;
  if (tid<8) sad[tid] = a_dst1[n*8+tid];
  for (int j=tid; j<deg; j+=256) ssrc[j] = csrc[base+j];
  __syncthreads();
  for (int idx=tid; idx<deg*8; idx+=256){
    int j = idx>>3, k = idx&7;
    float a = a_src1[ssrc[j]*8+k] + sad[k];
    sw[j][k] = (a>0.f) ? a : NEG*a;
  }
  __syncthreads();
  if (tid<8){
    int k = tid;
    float m = -1e30f;
    for (int j=0;j<deg;j++) m = fmaxf(m, sw[j][k]);
    float s = 0.f;
    for (int j=0;j<deg;j++){ float e = __expf(sw[j][k]-m); sw[j][k]=e; s+=e; }
    float inv = 1.f/(s + 1e-16f);
    for (int j=0;j<deg;j++) sw[j][k] *= inv;
  }
  __syncthreads();
  float acc[8] = {0,0,0,0,0,0,0,0};
  for (int j=0;j<deg;j++){
    short8 hv = *(const short8*)(h1T + (size_t)ssrc[j]*F1 + tid*8);
    float w0=sw[j][0], w1=sw[j][1], w2=sw[j][2], w3=sw[j][3];
    float w4=sw[j][4], w5=sw[j][5], w6=sw[j][6], w7=sw[j][7];
    acc[0] += w0*bf2f((ushort)hv[0]); acc[1] += w1*bf2f((ushort)hv[1]);
    acc[2] += w2*bf2f((ushort)hv[2]); acc[3] += w3*bf2f((ushort)hv[3]);
    acc[4] += w4*bf2f((ushort)hv[4]); acc[5] += w5*bf2f((ushort)hv[5]);
    acc[6] += w6*bf2f((ushort)hv[6]); acc[7] += w7*bf2f((ushort)hv[7]);
  }
#pragma unroll
  for (int k=0;k<8;k++){
    int col = (k<<8) + tid;
    float v = acc[k] + b1[col];
    v = (v>0.f) ? v : (__expf(v)-1.f);
    x2[(size_t)n*F1 + col] = f2bf(v);
  }
}

// ---------------- conv2 GEMM: MFMA bf16, fused attention dots ----------------
// A: x2 [20000][2048] bf16 row-major. BT: W2 [256][2048] bf16 (N-major).
// Tile 64x256xK32; 4 waves, each wave 64 rows x 64 cols (4x4 frags of 16x16).
__global__ __launch_bounds__(256) void k_gemm2m(const ushort* __restrict__ A,
    const ushort* __restrict__ BT, float* __restrict__ h2,
    const float* __restrict__ as2, const float* __restrict__ ad2,
    float* __restrict__ a_src2, float* __restrict__ a_dst2){
  __shared__ __align__(16) ushort As[64*32];    // 4 KB
  __shared__ __align__(16) ushort Bs[256*32];   // 16 KB
  int tid = threadIdx.x;
  int m0 = blockIdx.x*64;
  int w = tid>>6, l = tid&63;
  int lrow = l&15, lk = l>>4;

  // staging address precompute (pre-swizzled global source; linear LDS dest)
  int arow = tid>>2;
  int aslot = (tid&3) ^ ((arow>>1)&3);
  int agrow = m0 + arow; if (agrow >= N_NODES) agrow = N_NODES-1;
  const ushort* ag = A + (size_t)agrow*F1 + (aslot<<3);
  const ushort* bg0; const ushort* bg1; const ushort* bg2; const ushort* bg3;
  {
    int c0 = (tid>>2),       s0 = (tid&3) ^ ((c0>>1)&3);
    int c1 = 64 + (tid>>2),  s1 = (tid&3) ^ ((c1>>1)&3);
    int c2 = 128 + (tid>>2), s2 = (tid&3) ^ ((c2>>1)&3);
    int c3 = 192 + (tid>>2), s3 = (tid&3) ^ ((c3>>1)&3);
    bg0 = BT + (size_t)c0*F1 + (s0<<3);
    bg1 = BT + (size_t)c1*F1 + (s1<<3);
    bg2 = BT + (size_t)c2*F1 + (s2<<3);
    bg3 = BT + (size_t)c3*F1 + (s3<<3);
  }

  f32x4 acc[4][4] = {};

  for (int k0=0; k0<F1; k0+=32){
    gload16(ag  + k0, As + tid*8);
    gload16(bg0 + k0, Bs + (0*256+tid)*8);
    gload16(bg1 + k0, Bs + (1*256+tid)*8);
    gload16(bg2 + k0, Bs + (2*256+tid)*8);
    gload16(bg3 + k0, Bs + (3*256+tid)*8);
    __syncthreads();   // drains vmcnt: staged data visible
    short8 af[4], bfr[4];
#pragma unroll
    for (int m=0;m<4;m++){
      int r = (m<<4) + lrow;
      af[m] = *(const short8*)&As[r*32 + ((lk ^ ((r>>1)&3))<<3)];
    }
#pragma unroll
    for (int n=0;n<4;n++){
      int c = (w<<6) + (n<<4) + lrow;
      bfr[n] = *(const short8*)&Bs[c*32 + ((lk ^ ((c>>1)&3))<<3)];
    }
#pragma unroll
    for (int m=0;m<4;m++)
#pragma unroll
      for (int n=0;n<4;n++)
        acc[m][n] = __builtin_amdgcn_mfma_f32_16x16x32_bf16(af[m], bfr[n], acc[m][n], 0,0,0);
    __syncthreads();   // all ds_reads done before next overwrite
  }

  // epilogue: store h2 + fused attention dots (a_src2/a_dst2 partial sums)
  float s2v[4], d2v[4];
#pragma unroll
  for (int n=0;n<4;n++){
    int col = (w<<6) + (n<<4) + lrow;
    s2v[n] = as2[col]; d2v[n] = ad2[col];
  }
#pragma unroll
  for (int m=0;m<4;m++){
#pragma unroll
    for (int j=0;j<4;j++){
      int grow = m0 + (m<<4) + (lk<<2) + j;
      bool ok = grow < N_NODES;
      float ps=0.f, pd=0.f;
#pragma unroll
      for (int n=0;n<4;n++){
        float v = acc[m][n][j];
        ps += v*s2v[n]; pd += v*d2v[n];
        if (ok) h2[(size_t)grow*256 + (w<<6)+(n<<4)+lrow] = v;
      }
      ps += __shfl_xor(ps,8); ps += __shfl_xor(ps,4); ps += __shfl_xor(ps,2); ps += __shfl_xor(ps,1);
      pd += __shfl_xor(pd,8); pd += __shfl_xor(pd,4); pd += __shfl_xor(pd,2); pd += __shfl_xor(pd,1);
      if (ok && lrow==0){
        atomicAdd(&a_src2[grow], ps);
        atomicAdd(&a_dst2[grow], pd);
      }
    }
  }
}

// ---------------- conv2 aggregation → output ----------------
__global__ __launch_bounds__(256) void k_agg2(const int* __restrict__ rowptr, const int* __restrict__ csrc,
    const float* __restrict__ a_src2, const float* __restrict__ a_dst2, const float* __restrict__ h2,
    const float* __restrict__ b2, float* __restrict__ out){
  int n = blockIdx.x, tid = threadIdx.x;
  __shared__ int   ssrc[MAXDEG];
  __shared__ float sw[MAXDEG];
  int base = rowptr[n];
  int deg  = rowptr[n+1] - base;
  if (deg > MAXDEG) deg = MAXDEG;
  for (int j=tid; j<deg; j+=256) ssrc[j] = csrc[base+j];
  __syncthreads();
  if (tid < 64){
    float ad = a_dst2[n];
    float m = -1e30f;
    for (int j=tid; j<deg; j+=64){
      float a = a_src2[ssrc[j]] + ad;
      a = (a>0.f) ? a : NEG*a;
      sw[j] = a; m = fmaxf(m, a);
    }
    for (int off=32; off; off>>=1) m = fmaxf(m, __shfl_xor(m,off));
    float s = 0.f;
    for (int j=tid; j<deg; j+=64){ float e = __expf(sw[j]-m); sw[j]=e; s+=e; }
    for (int off=32; off; off>>=1) s += __shfl_xor(s,off);
    float inv = 1.f/(s + 1e-16f);
    for (int j=tid; j<deg; j+=64) sw[j] *= inv;
  }
  __syncthreads();
  float acc = 0.f;
  for (int j=0;j<deg;j++) acc += sw[j]*h2[(size_t)ssrc[j]*256 + tid];
  out[(size_t)n*256 + tid] = acc + b2[tid];
}

extern "C" void kernel_launch(void* const* d_in, const int* in_sizes, int n_in,
                              void* d_out, int out_size, void* d_ws, size_t ws_size,
                              hipStream_t stream){
  const float* x      = (const float*)d_in[0];
  const int*   ei     = (const int*)  d_in[1];
  const float* W1     = (const float*)d_in[2];
  const float* att_s1 = (const float*)d_in[3];
  const float* att_d1 = (const float*)d_in[4];
  const float* b1     = (const float*)d_in[5];
  const float* W2     = (const float*)d_in[6];
  const float* att_s2 = (const float*)d_in[7];
  const float* att_d2 = (const float*)d_in[8];
  const float* b2     = (const float*)d_in[9];
  float* out = (float*)d_out;

  char* p = (char*)d_ws;
  auto alloc = [&](size_t bytes)->char*{ char* r = p; p += (bytes + 255) & ~(size_t)255; return r; };
  ushort* h1T   = (ushort*)alloc((size_t)N_NODES*F1*2);
  ushort* x2    = (ushort*)alloc((size_t)N_NODES*F1*2);
  ushort* W2bT  = (ushort*)alloc((size_t)F1*256*2);
  float*  h2    = (float*) alloc((size_t)N_NODES*256*4);
  float*  a_src1= (float*) alloc((size_t)N_NODES*8*4);
  float*  a_dst1= (float*) alloc((size_t)N_NODES*8*4);
  float*  a_src2= (float*) alloc((size_t)N_NODES*4);
  float*  a_dst2= (float*) alloc((size_t)N_NODES*4);
  int*    deg   = (int*)   alloc((size_t)N_NODES*4);
  int*    rowptr= (int*)   alloc((size_t)(N_NODES+1)*4);
  int*    cursor= (int*)   alloc((size_t)N_NODES*4);
  int*    csrc  = (int*)   alloc((size_t)E_TOT*4);

  hipMemsetAsync(deg,    0, (size_t)N_NODES*4, stream);
  hipMemsetAsync(a_src2, 0, (size_t)N_NODES*4, stream);
  hipMemsetAsync(a_dst2, 0, (size_t)N_NODES*4, stream);
  k_count  <<<(E_TOT+255)/256, 256, 0, stream>>>(ei, deg);
  k_scan   <<<1, 1024, 0, stream>>>(deg, rowptr, cursor);
  k_scatter<<<(E_TOT+255)/256, 256, 0, stream>>>(ei, cursor, csrc);
  k_gemm1  <<<N_NODES, 256, 0, stream>>>(x, W1, att_s1, att_d1, h1T, a_src1, a_dst1);
  k_wT     <<<F1/64, 256, 0, stream>>>(W2, W2bT);
  k_agg1   <<<N_NODES, 256, 0, stream>>>(rowptr, csrc, a_src1, a_dst1, h1T, b1, x2);
  k_gemm2m <<<(N_NODES+63)/64, 256, 0, stream>>>(x2, W2bT, h2, att_s2, att_d2, a_src2, a_dst2);
  k_agg2   <<<N_NODES, 256, 0, stream>>>(rowptr, csrc, a_src2, a_dst2, h2, b2, out);
}

// Round 3
// 241.288 us; speedup vs baseline: 2.5362x; 1.5842x over previous
//
#include <hip/hip_runtime.h>
#include <hip/hip_bf16.h>

#define N_NODES 20000
#define E_ORIG  160000
#define E_TOT   180000
#define HEADS   8
#define HID     256
#define F1      2048   // HEADS*HID
#define NEG     0.2f
#define MAXDEG  96
#define GAGG    8

typedef __attribute__((ext_vector_type(8))) short  short8;
typedef __attribute__((ext_vector_type(4))) float  f32x4;

__device__ inline float bf2f(ushort u){ union{unsigned u32; float f;} v; v.u32=((unsigned)u)<<16; return v.f; }
__device__ inline ushort f2bf(float f){
  union{float f; unsigned u;} v; v.f=f;
  unsigned lsb=(v.u>>16)&1u; v.u += 0x7fffu + lsb; return (ushort)(v.u>>16);
}

__device__ inline void gload16(const ushort* g, ushort* s){
  __builtin_amdgcn_global_load_lds((const __attribute__((address_space(1))) unsigned int*)g,
                                   (__attribute__((address_space(3))) unsigned int*)s, 16, 0, 0);
}

// ---------------- CSR build ----------------
__global__ void k_count(const int* __restrict__ ei, int* __restrict__ deg){
  int e = blockIdx.x*256 + threadIdx.x;
  if (e >= E_TOT) return;
  int d = (e < E_ORIG) ? ei[E_ORIG + e] : (e - E_ORIG);
  atomicAdd(&deg[d], 1);
}

__global__ __launch_bounds__(1024) void k_scan(const int* __restrict__ deg,
                                               int* __restrict__ rowptr,
                                               int* __restrict__ cursor){
  __shared__ int s[1024];
  __shared__ int base;
  int tid = threadIdx.x;
  if (tid==0) base = 0;
  __syncthreads();
  for (int start=0; start<N_NODES; start+=1024){
    int i = start + tid;
    int v = (i<N_NODES) ? deg[i] : 0;
    s[tid] = v; __syncthreads();
    for (int off=1; off<1024; off<<=1){
      int t = (tid>=off) ? s[tid-off] : 0;
      __syncthreads();
      s[tid] += t;
      __syncthreads();
    }
    if (i<N_NODES){ int ex = base + s[tid] - v; rowptr[i]=ex; cursor[i]=ex; }
    __syncthreads();
    if (tid==0) base += s[1023];
    __syncthreads();
  }
  if (tid==0) rowptr[N_NODES] = base;
}

__global__ void k_scatter(const int* __restrict__ ei, int* __restrict__ cursor,
                          int* __restrict__ csrc){
  int e = blockIdx.x*256 + threadIdx.x;
  if (e >= E_TOT) return;
  int s, d;
  if (e < E_ORIG){ s = ei[e]; d = ei[E_ORIG + e]; }
  else           { s = d = e - E_ORIG; }
  int pos = atomicAdd(&cursor[d], 1);
  csrc[pos] = s;
}

// ---------------- factorized attention-dot weights: ws/wd[k][i] = sum_c W1[i][k*256+c]*att[k][c] ----------------
__global__ __launch_bounds__(256) void k_prep(const float* __restrict__ W1,
    const float* __restrict__ as1, const float* __restrict__ ad1,
    float* __restrict__ wsv, float* __restrict__ wdv){
  int tid = threadIdx.x;
  int lane = tid&63, wv = tid>>6;
  for (int kk=wv; kk<8; kk+=4){
    for (int i=0;i<7;i++){
      float v1=0.f, v2=0.f;
      for (int c=lane;c<256;c+=64){
        float w = W1[i*F1 + kk*256 + c];
        v1 += w*as1[kk*256+c];
        v2 += w*ad1[kk*256+c];
      }
      for (int off=32;off;off>>=1){ v1+=__shfl_down(v1,off); v2+=__shfl_down(v2,off); }
      if (!lane){ wsv[kk*8+i]=v1; wdv[kk*8+i]=v2; }
    }
    if (!lane){ wsv[kk*8+7]=0.f; wdv[kk*8+7]=0.f; }
  }
}

// ---------------- per-node attention logits from rank-7 factorization ----------------
__global__ __launch_bounds__(256) void k_dots1(const float* __restrict__ x,
    const float* __restrict__ wsv, const float* __restrict__ wdv,
    float* __restrict__ a_src1, float* __restrict__ a_dst1){
  __shared__ float s_ws[64], s_wd[64];
  int tid = threadIdx.x;
  if (tid < 64){ s_ws[tid]=wsv[tid]; s_wd[tid]=wdv[tid]; }
  __syncthreads();
  int nl = tid>>3, k = tid&7;
  int n = blockIdx.x*32 + nl;
  if (n < N_NODES){
    float s=0.f, d=0.f;
#pragma unroll
    for (int i=0;i<7;i++){
      float xv = x[n*7+i];
      s += xv*s_ws[k*8+i]; d += xv*s_wd[k*8+i];
    }
    a_src1[n*8+k]=s; a_dst1[n*8+k]=d;
  }
}

// ---------------- W2 -> bf16 transposed [256][2048] ----------------
__global__ __launch_bounds__(256) void k_wT(const float* __restrict__ W2, ushort* __restrict__ BT){
  __shared__ ushort sh[256][65];
  int k0 = blockIdx.x*64, t = threadIdx.x;
  for (int kk=0; kk<64; kk++) sh[t][kk] = f2bf(W2[(size_t)(k0+kk)*256 + t]);
  __syncthreads();
#pragma unroll
  for (int c8=0; c8<8; c8++){
    short8 v;
#pragma unroll
    for (int j=0;j<8;j++) v[j] = (short)sh[t][c8*8+j];
    *(short8*)&BT[(size_t)t*F1 + k0 + c8*8] = v;
  }
}

// ---------------- conv1: softmax in 7-dim space + fused W1 apply + bias + ELU ----------------
// agg[n] = (sum_j alpha_j x[src_j]) @ W1  (linearity of aggregation; h1 never materialized)
__global__ __launch_bounds__(256) void k_agg1x(const int* __restrict__ rowptr, const int* __restrict__ csrc,
    const float* __restrict__ a_src1, const float* __restrict__ a_dst1,
    const float* __restrict__ x, const float* __restrict__ W1, const float* __restrict__ b1,
    ushort* __restrict__ x2){
  int tid = threadIdx.x;
  int k = tid>>5, c0 = (tid&31)<<3;   // head, col-base (8 consecutive cols)
  // W1 columns for this thread, fp32 in registers (reused for GAGG nodes)
  f32x4 w1a[7], w1b[7];
#pragma unroll
  for (int i=0;i<7;i++){
    const float* p = W1 + i*F1 + (k<<8) + c0;
    w1a[i] = *(const f32x4*)p; w1b[i] = *(const f32x4*)(p+4);
  }
  f32x4 b1a = *(const f32x4*)(b1 + (k<<8)+c0);
  f32x4 b1b = *(const f32x4*)(b1 + (k<<8)+c0+4);

  __shared__ int   ssrc[MAXDEG];
  __shared__ float sw[MAXDEG][8];
  __shared__ float xs[MAXDEG][8];
  __shared__ float xagg[8][8];
  __shared__ float sinv[8];
  __shared__ float sad[8];

  for (int g=0; g<GAGG; g++){
    int n = blockIdx.x*GAGG + g;
    if (n >= N_NODES) break;
    int base = rowptr[n];
    int deg  = rowptr[n+1]-base; if (deg>MAXDEG) deg=MAXDEG;
    __syncthreads();                    // protect LDS reuse from previous node
    for (int j=tid; j<deg; j+=256) ssrc[j]=csrc[base+j];
    if (tid<8) sad[tid]=a_dst1[n*8+tid];
    __syncthreads();
    for (int idx=tid; idx<deg*8; idx+=256){
      int j=idx>>3, kk=idx&7;
      int s = ssrc[j];
      float a = a_src1[s*8+kk] + sad[kk];
      sw[j][kk] = (a>0.f)?a:NEG*a;
      if (kk<7) xs[j][kk] = x[s*7+kk];
    }
    __syncthreads();
    if (tid < 64){                      // wave 0: per-head softmax (unnormalized exp + inv-sum)
      int kk = tid&7, jj = tid>>3;
      float m = -1e30f;
      for (int j=jj; j<deg; j+=8) m = fmaxf(m, sw[j][kk]);
      m = fmaxf(m, __shfl_xor(m, 8));
      m = fmaxf(m, __shfl_xor(m, 16));
      m = fmaxf(m, __shfl_xor(m, 32));
      float s = 0.f;
      for (int j=jj; j<deg; j+=8){ float e=__expf(sw[j][kk]-m); sw[j][kk]=e; s+=e; }
      s += __shfl_xor(s, 8); s += __shfl_xor(s, 16); s += __shfl_xor(s, 32);
      if (jj==0) sinv[kk] = 1.f/(s+1e-16f);
    }
    __syncthreads();
    if (tid < 64){                      // xagg[k][i] = sum_j alpha_jk * x[src_j][i]
      int kk=tid>>3, i=tid&7;
      if (i<7){
        float acc=0.f;
        for (int j=0;j<deg;j++) acc += sw[j][kk]*xs[j][i];
        xagg[kk][i] = acc*sinv[kk];
      }
    }
    __syncthreads();
    f32x4 ha = b1a, hb = b1b;
#pragma unroll
    for (int i=0;i<7;i++){
      float xv = xagg[k][i];
      ha += xv*w1a[i]; hb += xv*w1b[i];
    }
    short8 o;
#pragma unroll
    for (int j=0;j<4;j++){
      float v = ha[j]; v = (v>0.f)?v:(__expf(v)-1.f); o[j]=(short)f2bf(v);
    }
#pragma unroll
    for (int j=0;j<4;j++){
      float v = hb[j]; v = (v>0.f)?v:(__expf(v)-1.f); o[4+j]=(short)f2bf(v);
    }
    *(short8*)(x2 + (size_t)n*F1 + (k<<8) + c0) = o;
  }
}

// ---------------- conv2 GEMM: MFMA bf16, BM=32 BK=64, fused attention dots, bf16 h2 ----------------
__global__ __launch_bounds__(256) void k_gemm2m(const ushort* __restrict__ A,
    const ushort* __restrict__ BT, ushort* __restrict__ h2b,
    const float* __restrict__ as2, const float* __restrict__ ad2,
    float* __restrict__ a_src2, float* __restrict__ a_dst2){
  __shared__ __align__(16) ushort As[32*64];    // 4 KB
  __shared__ __align__(16) ushort Bs[256*64];   // 32 KB
  int tid = threadIdx.x;
  int m0 = blockIdx.x*32;
  int w = tid>>6, l = tid&63;
  int lrow = l&15, lk = l>>4;

  // staging: linear LDS dest, inverse-swizzled global source (slot ^= row&7)
  int ar = tid>>3, aslot = (tid&7) ^ (ar&7);
  int agrow = m0 + ar; if (agrow >= N_NODES) agrow = N_NODES-1;
  const ushort* ag = A + (size_t)agrow*F1 + (aslot<<3);
  const ushort* bg[8];
#pragma unroll
  for (int rep=0; rep<8; rep++){
    int lin = rep*256 + tid;
    int c = lin>>3, slot = (lin&7) ^ (c&7);
    bg[rep] = BT + (size_t)c*F1 + (slot<<3);
  }

  f32x4 acc[2][4] = {};

  for (int k0=0; k0<F1; k0+=64){
    gload16(ag + k0, As + tid*8);
#pragma unroll
    for (int rep=0; rep<8; rep++)
      gload16(bg[rep] + k0, Bs + (rep*256+tid)*8);
    __syncthreads();
    short8 af[2][2], bfr[4][2];
#pragma unroll
    for (int m=0;m<2;m++){
      int r = (m<<4) + lrow;
#pragma unroll
      for (int kk=0;kk<2;kk++)
        af[m][kk] = *(const short8*)&As[r*64 + ((((kk<<2)|lk) ^ (r&7))<<3)];
    }
#pragma unroll
    for (int n=0;n<4;n++){
      int c = (w<<6) + (n<<4) + lrow;
#pragma unroll
      for (int kk=0;kk<2;kk++)
        bfr[n][kk] = *(const short8*)&Bs[c*64 + ((((kk<<2)|lk) ^ (c&7))<<3)];
    }
#pragma unroll
    for (int kk=0;kk<2;kk++)
#pragma unroll
      for (int m=0;m<2;m++)
#pragma unroll
        for (int n=0;n<4;n++)
          acc[m][n] = __builtin_amdgcn_mfma_f32_16x16x32_bf16(af[m][kk], bfr[n][kk], acc[m][n], 0,0,0);
    __syncthreads();
  }

  // epilogue: bf16 h2 store + fused attention dots
  float s2v[4], d2v[4];
#pragma unroll
  for (int n=0;n<4;n++){
    int col = (w<<6)+(n<<4)+lrow;
    s2v[n]=as2[col]; d2v[n]=ad2[col];
  }
#pragma unroll
  for (int m=0;m<2;m++){
#pragma unroll
    for (int j=0;j<4;j++){
      int grow = m0 + (m<<4) + (lk<<2) + j;
      bool ok = grow < N_NODES;
      float ps=0.f, pd=0.f;
#pragma unroll
      for (int n=0;n<4;n++){
        float v = acc[m][n][j];
        ps += v*s2v[n]; pd += v*d2v[n];
        if (ok) h2b[(size_t)grow*256 + (w<<6)+(n<<4)+lrow] = f2bf(v);
      }
      ps += __shfl_xor(ps,8); ps += __shfl_xor(ps,4); ps += __shfl_xor(ps,2); ps += __shfl_xor(ps,1);
      pd += __shfl_xor(pd,8); pd += __shfl_xor(pd,4); pd += __shfl_xor(pd,2); pd += __shfl_xor(pd,1);
      if (ok && lrow==0){
        atomicAdd(&a_src2[grow], ps);
        atomicAdd(&a_dst2[grow], pd);
      }
    }
  }
}

// ---------------- conv2 aggregation → output ----------------
__global__ __launch_bounds__(256) void k_agg2(const int* __restrict__ rowptr, const int* __restrict__ csrc,
    const float* __restrict__ a_src2, const float* __restrict__ a_dst2, const ushort* __restrict__ h2b,
    const float* __restrict__ b2, float* __restrict__ out){
  int n = blockIdx.x, tid = threadIdx.x;
  __shared__ int   ssrc[MAXDEG];
  __shared__ float sw[MAXDEG];
  int base = rowptr[n];
  int deg  = rowptr[n+1] - base;
  if (deg > MAXDEG) deg = MAXDEG;
  for (int j=tid; j<deg; j+=256) ssrc[j] = csrc[base+j];
  __syncthreads();
  if (tid < 64){
    float ad = a_dst2[n];
    float m = -1e30f;
    for (int j=tid; j<deg; j+=64){
      float a = a_src2[ssrc[j]] + ad;
      a = (a>0.f) ? a : NEG*a;
      sw[j] = a; m = fmaxf(m, a);
    }
    for (int off=32; off; off>>=1) m = fmaxf(m, __shfl_xor(m,off));
    float s = 0.f;
    for (int j=tid; j<deg; j+=64){ float e = __expf(sw[j]-m); sw[j]=e; s+=e; }
    for (int off=32; off; off>>=1) s += __shfl_xor(s,off);
    float inv = 1.f/(s + 1e-16f);
    for (int j=tid; j<deg; j+=64) sw[j] *= inv;
  }
  __syncthreads();
  float acc = 0.f;
  for (int j=0;j<deg;j++) acc += sw[j]*bf2f(h2b[(size_t)ssrc[j]*256 + tid]);
  out[(size_t)n*256 + tid] = acc + b2[tid];
}

extern "C" void kernel_launch(void* const* d_in, const int* in_sizes, int n_in,
                              void* d_out, int out_size, void* d_ws, size_t ws_size,
                              hipStream_t stream){
  const float* x      = (const float*)d_in[0];
  const int*   ei     = (const int*)  d_in[1];
  const float* W1     = (const float*)d_in[2];
  const float* att_s1 = (const float*)d_in[3];
  const float* att_d1 = (const float*)d_in[4];
  const float* b1     = (const float*)d_in[5];
  const float* W2     = (const float*)d_in[6];
  const float* att_s2 = (const float*)d_in[7];
  const float* att_d2 = (const float*)d_in[8];
  const float* b2     = (const float*)d_in[9];
  float* out = (float*)d_out;

  char* p = (char*)d_ws;
  auto alloc = [&](size_t bytes)->char*{ char* r = p; p += (bytes + 255) & ~(size_t)255; return r; };
  ushort* x2    = (ushort*)alloc((size_t)N_NODES*F1*2);
  ushort* W2bT  = (ushort*)alloc((size_t)F1*256*2);
  ushort* h2b   = (ushort*)alloc((size_t)N_NODES*256*2);
  float*  a_src1= (float*) alloc((size_t)N_NODES*8*4);
  float*  a_dst1= (float*) alloc((size_t)N_NODES*8*4);
  float*  a_src2= (float*) alloc((size_t)N_NODES*4);
  float*  a_dst2= (float*) alloc((size_t)N_NODES*4);
  float*  wsv   = (float*) alloc(64*4);
  float*  wdv   = (float*) alloc(64*4);
  int*    deg   = (int*)   alloc((size_t)N_NODES*4);
  int*    rowptr= (int*)   alloc((size_t)(N_NODES+1)*4);
  int*    cursor= (int*)   alloc((size_t)N_NODES*4);
  int*    csrc  = (int*)   alloc((size_t)E_TOT*4);

  hipMemsetAsync(deg,    0, (size_t)N_NODES*4, stream);
  hipMemsetAsync(a_src2, 0, (size_t)N_NODES*4, stream);
  hipMemsetAsync(a_dst2, 0, (size_t)N_NODES*4, stream);
  k_count  <<<(E_TOT+255)/256, 256, 0, stream>>>(ei, deg);
  k_scan   <<<1, 1024, 0, stream>>>(deg, rowptr, cursor);
  k_scatter<<<(E_TOT+255)/256, 256, 0, stream>>>(ei, cursor, csrc);
  k_prep   <<<1, 256, 0, stream>>>(W1, att_s1, att_d1, wsv, wdv);
  k_dots1  <<<(N_NODES+31)/32, 256, 0, stream>>>(x, wsv, wdv, a_src1, a_dst1);
  k_wT     <<<F1/64, 256, 0, stream>>>(W2, W2bT);
  k_agg1x  <<<(N_NODES+GAGG-1)/GAGG, 256, 0, stream>>>(rowptr, csrc, a_src1, a_dst1, x, W1, b1, x2);
  k_gemm2m <<<(N_NODES+31)/32, 256, 0, stream>>>(x2, W2bT, h2b, att_s2, att_d2, a_src2, a_dst2);
  k_agg2   <<<N_NODES, 256, 0, stream>>>(rowptr, csrc, a_src2, a_dst2, h2b, b2, out);
}

// Round 4
// 232.227 us; speedup vs baseline: 2.6351x; 1.0390x over previous
//
#include <hip/hip_runtime.h>
#include <hip/hip_bf16.h>

#define N_NODES 20000
#define E_ORIG  160000
#define E_TOT   180000
#define HEADS   8
#define HID     256
#define F1      2048   // HEADS*HID
#define NEG     0.2f
#define MAXDEG  96
#define NAPP    32

typedef __attribute__((ext_vector_type(8))) short  short8;
typedef __attribute__((ext_vector_type(4))) float  f32x4;

__device__ inline float bf2f(ushort u){ union{unsigned u32; float f;} v; v.u32=((unsigned)u)<<16; return v.f; }
__device__ inline ushort f2bf(float f){
  union{float f; unsigned u;} v; v.f=f;
  unsigned lsb=(v.u>>16)&1u; v.u += 0x7fffu + lsb; return (ushort)(v.u>>16);
}

__device__ inline void gload16(const ushort* g, ushort* s){
  __builtin_amdgcn_global_load_lds((const __attribute__((address_space(1))) unsigned int*)g,
                                   (__attribute__((address_space(3))) unsigned int*)s, 16, 0, 0);
}

// ---------------- CSR build ----------------
__global__ void k_count(const int* __restrict__ ei, int* __restrict__ deg){
  int e = blockIdx.x*256 + threadIdx.x;
  if (e >= E_TOT) return;
  int d = (e < E_ORIG) ? ei[E_ORIG + e] : (e - E_ORIG);
  atomicAdd(&deg[d], 1);
}

__global__ __launch_bounds__(1024) void k_scan(const int* __restrict__ deg,
                                               int* __restrict__ rowptr,
                                               int* __restrict__ cursor){
  __shared__ int s[1024];
  __shared__ int base;
  int tid = threadIdx.x;
  if (tid==0) base = 0;
  __syncthreads();
  for (int start=0; start<N_NODES; start+=1024){
    int i = start + tid;
    int v = (i<N_NODES) ? deg[i] : 0;
    s[tid] = v; __syncthreads();
    for (int off=1; off<1024; off<<=1){
      int t = (tid>=off) ? s[tid-off] : 0;
      __syncthreads();
      s[tid] += t;
      __syncthreads();
    }
    if (i<N_NODES){ int ex = base + s[tid] - v; rowptr[i]=ex; cursor[i]=ex; }
    __syncthreads();
    if (tid==0) base += s[1023];
    __syncthreads();
  }
  if (tid==0) rowptr[N_NODES] = base;
}

__global__ void k_scatter(const int* __restrict__ ei, int* __restrict__ cursor,
                          int* __restrict__ csrc){
  int e = blockIdx.x*256 + threadIdx.x;
  if (e >= E_TOT) return;
  int s, d;
  if (e < E_ORIG){ s = ei[e]; d = ei[E_ORIG + e]; }
  else           { s = d = e - E_ORIG; }
  int pos = atomicAdd(&cursor[d], 1);
  csrc[pos] = s;
}

// ---------------- factorized attention-dot weights ----------------
__global__ __launch_bounds__(256) void k_prep(const float* __restrict__ W1,
    const float* __restrict__ as1, const float* __restrict__ ad1,
    float* __restrict__ wsv, float* __restrict__ wdv){
  int tid = threadIdx.x;
  int lane = tid&63, wv = tid>>6;
  for (int kk=wv; kk<8; kk+=4){
    for (int i=0;i<7;i++){
      float v1=0.f, v2=0.f;
      for (int c=lane;c<256;c+=64){
        float w = W1[i*F1 + kk*256 + c];
        v1 += w*as1[kk*256+c];
        v2 += w*ad1[kk*256+c];
      }
      for (int off=32;off;off>>=1){ v1+=__shfl_down(v1,off); v2+=__shfl_down(v2,off); }
      if (!lane){ wsv[kk*8+i]=v1; wdv[kk*8+i]=v2; }
    }
    if (!lane){ wsv[kk*8+7]=0.f; wdv[kk*8+7]=0.f; }
  }
}

// ---------------- per-node attention logits ----------------
__global__ __launch_bounds__(256) void k_dots1(const float* __restrict__ x,
    const float* __restrict__ wsv, const float* __restrict__ wdv,
    float* __restrict__ a_src1, float* __restrict__ a_dst1){
  __shared__ float s_ws[64], s_wd[64];
  int tid = threadIdx.x;
  if (tid < 64){ s_ws[tid]=wsv[tid]; s_wd[tid]=wdv[tid]; }
  __syncthreads();
  int nl = tid>>3, k = tid&7;
  int n = blockIdx.x*32 + nl;
  if (n < N_NODES){
    float s=0.f, d=0.f;
#pragma unroll
    for (int i=0;i<7;i++){
      float xv = x[n*7+i];
      s += xv*s_ws[k*8+i]; d += xv*s_wd[k*8+i];
    }
    a_src1[n*8+k]=s; a_dst1[n*8+k]=d;
  }
}

// ---------------- W2 -> bf16 transposed [256][2048] ----------------
__global__ __launch_bounds__(256) void k_wT(const float* __restrict__ W2, ushort* __restrict__ BT){
  __shared__ ushort sh[256][65];
  int k0 = blockIdx.x*64, t = threadIdx.x;
  for (int kk=0; kk<64; kk++) sh[t][kk] = f2bf(W2[(size_t)(k0+kk)*256 + t]);
  __syncthreads();
#pragma unroll
  for (int c8=0; c8<8; c8++){
    short8 v;
#pragma unroll
    for (int j=0;j<8;j++) v[j] = (short)sh[t][c8*8+j];
    *(short8*)&BT[(size_t)t*F1 + k0 + c8*8] = v;
  }
}

// ---------------- conv1 softmax + 7-dim aggregation: one wave per node ----------------
__global__ __launch_bounds__(64) void k_soft1(const int* __restrict__ rowptr, const int* __restrict__ csrc,
    const float* __restrict__ a_src1, const float* __restrict__ a_dst1,
    const float* __restrict__ x, float* __restrict__ xagg){
  int n = blockIdx.x, lane = threadIdx.x;
  __shared__ float lw[MAXDEG][8];
  __shared__ float lx[MAXDEG][8];
  int base = rowptr[n];
  int deg  = rowptr[n+1]-base; if (deg>MAXDEG) deg=MAXDEG;
  f32x4 ad0 = *(const f32x4*)(a_dst1 + n*8);
  f32x4 ad1 = *(const f32x4*)(a_dst1 + n*8 + 4);
  float l[2][8], xv[2][7];
  bool valid[2];
#pragma unroll
  for (int t=0;t<2;t++){
    int j = lane + 64*t;
    bool v = j<deg; valid[t]=v;
    int src = v ? csrc[base+j] : 0;
    f32x4 s0, s1;
    if (v){ s0 = *(const f32x4*)(a_src1+(size_t)src*8); s1 = *(const f32x4*)(a_src1+(size_t)src*8+4); }
    else  { s0 = f32x4{0,0,0,0}; s1 = f32x4{0,0,0,0}; }
#pragma unroll
    for (int k=0;k<4;k++){
      float a = s0[k]+ad0[k]; a=(a>0.f)?a:NEG*a; l[t][k]   = v?a:-1e30f;
      float b = s1[k]+ad1[k]; b=(b>0.f)?b:NEG*b; l[t][4+k] = v?b:-1e30f;
    }
#pragma unroll
    for (int i=0;i<7;i++) xv[t][i] = v ? x[(size_t)src*7+i] : 0.f;
  }
  float m[8], sinv[8];
#pragma unroll
  for (int k=0;k<8;k++){
    float mm = fmaxf(l[0][k], l[1][k]);
    for (int off=32; off; off>>=1) mm = fmaxf(mm, __shfl_xor(mm,off));
    m[k]=mm;
  }
  float e[2][8];
#pragma unroll
  for (int k=0;k<8;k++){
    e[0][k] = valid[0]?__expf(l[0][k]-m[k]):0.f;
    e[1][k] = valid[1]?__expf(l[1][k]-m[k]):0.f;
    float ss = e[0][k]+e[1][k];
    for (int off=32; off; off>>=1) ss += __shfl_xor(ss,off);
    sinv[k] = 1.f/(ss+1e-16f);
  }
#pragma unroll
  for (int t=0;t<2;t++){
    int j = lane+64*t;
    if (j<deg){
#pragma unroll
      for (int k=0;k<8;k++) lw[j][k] = e[t][k]*sinv[k];
#pragma unroll
      for (int i=0;i<7;i++) lx[j][i] = xv[t][i];
    }
  }
  __syncthreads();
  int kk = lane>>3, i = lane&7;
  float acc = 0.f;
  if (i<7){
    for (int j=0;j<deg;j++) acc += lw[j][kk]*lx[j][i];
  }
  xagg[(size_t)n*64 + lane] = acc;
}

// ---------------- conv1 apply: x2 = ELU(xagg @ W1 + b1), bf16 ----------------
__global__ __launch_bounds__(256) void k_apply1(const float* __restrict__ xagg,
    const float* __restrict__ W1, const float* __restrict__ b1, ushort* __restrict__ x2){
  int tid = threadIdx.x;
  int k = tid>>5, c0 = (tid&31)<<3;
  f32x4 w1a[7], w1b[7];
#pragma unroll
  for (int i=0;i<7;i++){
    const float* p = W1 + i*F1 + (k<<8) + c0;
    w1a[i] = *(const f32x4*)p; w1b[i] = *(const f32x4*)(p+4);
  }
  f32x4 b1a = *(const f32x4*)(b1 + (k<<8)+c0);
  f32x4 b1b = *(const f32x4*)(b1 + (k<<8)+c0+4);

  __shared__ float sxa[NAPP*64];
  int nb = blockIdx.x*NAPP;
  for (int idx=tid; idx<NAPP*64; idx+=256)
    sxa[idx] = xagg[(size_t)nb*64 + idx];
  __syncthreads();
#pragma unroll 4
  for (int g=0; g<NAPP; g++){
    int n = nb+g;
    const float* xa = &sxa[g*64 + (k<<3)];
    f32x4 ha=b1a, hb=b1b;
#pragma unroll
    for (int i=0;i<7;i++){
      float xv = xa[i];
      ha += xv*w1a[i]; hb += xv*w1b[i];
    }
    short8 o;
#pragma unroll
    for (int j=0;j<4;j++){ float v=ha[j]; v=(v>0.f)?v:(__expf(v)-1.f); o[j]  =(short)f2bf(v); }
#pragma unroll
    for (int j=0;j<4;j++){ float v=hb[j]; v=(v>0.f)?v:(__expf(v)-1.f); o[4+j]=(short)f2bf(v); }
    *(short8*)(x2 + (size_t)n*F1 + (k<<8) + c0) = o;
  }
}

// ---------------- conv2 GEMM: MFMA bf16, BM=32 BK=64, fused attention dots, bf16 h2 ----------------
__global__ __launch_bounds__(256) void k_gemm2m(const ushort* __restrict__ A,
    const ushort* __restrict__ BT, ushort* __restrict__ h2b,
    const float* __restrict__ as2, const float* __restrict__ ad2,
    float* __restrict__ a_src2, float* __restrict__ a_dst2){
  __shared__ __align__(16) ushort As[32*64];    // 4 KB
  __shared__ __align__(16) ushort Bs[256*64];   // 32 KB
  int tid = threadIdx.x;
  int m0 = blockIdx.x*32;
  int w = tid>>6, l = tid&63;
  int lrow = l&15, lk = l>>4;

  int ar = tid>>3, aslot = (tid&7) ^ (ar&7);
  int agrow = m0 + ar; if (agrow >= N_NODES) agrow = N_NODES-1;
  const ushort* ag = A + (size_t)agrow*F1 + (aslot<<3);
  const ushort* bg[8];
#pragma unroll
  for (int rep=0; rep<8; rep++){
    int lin = rep*256 + tid;
    int c = lin>>3, slot = (lin&7) ^ (c&7);
    bg[rep] = BT + (size_t)c*F1 + (slot<<3);
  }

  f32x4 acc[2][4] = {};

  for (int k0=0; k0<F1; k0+=64){
    gload16(ag + k0, As + tid*8);
#pragma unroll
    for (int rep=0; rep<8; rep++)
      gload16(bg[rep] + k0, Bs + (rep*256+tid)*8);
    __syncthreads();
    short8 af[2][2], bfr[4][2];
#pragma unroll
    for (int m=0;m<2;m++){
      int r = (m<<4) + lrow;
#pragma unroll
      for (int kk=0;kk<2;kk++)
        af[m][kk] = *(const short8*)&As[r*64 + ((((kk<<2)|lk) ^ (r&7))<<3)];
    }
#pragma unroll
    for (int n=0;n<4;n++){
      int c = (w<<6) + (n<<4) + lrow;
#pragma unroll
      for (int kk=0;kk<2;kk++)
        bfr[n][kk] = *(const short8*)&Bs[c*64 + ((((kk<<2)|lk) ^ (c&7))<<3)];
    }
#pragma unroll
    for (int kk=0;kk<2;kk++)
#pragma unroll
      for (int m=0;m<2;m++)
#pragma unroll
        for (int n=0;n<4;n++)
          acc[m][n] = __builtin_amdgcn_mfma_f32_16x16x32_bf16(af[m][kk], bfr[n][kk], acc[m][n], 0,0,0);
    __syncthreads();
  }

  float s2v[4], d2v[4];
#pragma unroll
  for (int n=0;n<4;n++){
    int col = (w<<6)+(n<<4)+lrow;
    s2v[n]=as2[col]; d2v[n]=ad2[col];
  }
#pragma unroll
  for (int m=0;m<2;m++){
#pragma unroll
    for (int j=0;j<4;j++){
      int grow = m0 + (m<<4) + (lk<<2) + j;
      bool ok = grow < N_NODES;
      float ps=0.f, pd=0.f;
#pragma unroll
      for (int n=0;n<4;n++){
        float v = acc[m][n][j];
        ps += v*s2v[n]; pd += v*d2v[n];
        if (ok) h2b[(size_t)grow*256 + (w<<6)+(n<<4)+lrow] = f2bf(v);
      }
      ps += __shfl_xor(ps,8); ps += __shfl_xor(ps,4); ps += __shfl_xor(ps,2); ps += __shfl_xor(ps,1);
      pd += __shfl_xor(pd,8); pd += __shfl_xor(pd,4); pd += __shfl_xor(pd,2); pd += __shfl_xor(pd,1);
      if (ok && lrow==0){
        atomicAdd(&a_src2[grow], ps);
        atomicAdd(&a_dst2[grow], pd);
      }
    }
  }
}

// ---------------- conv2 aggregation → output ----------------
__global__ __launch_bounds__(256) void k_agg2(const int* __restrict__ rowptr, const int* __restrict__ csrc,
    const float* __restrict__ a_src2, const float* __restrict__ a_dst2, const ushort* __restrict__ h2b,
    const float* __restrict__ b2, float* __restrict__ out){
  int n = blockIdx.x, tid = threadIdx.x;
  __shared__ int   ssrc[MAXDEG];
  __shared__ float sw[MAXDEG];
  int base = rowptr[n];
  int deg  = rowptr[n+1] - base;
  if (deg > MAXDEG) deg = MAXDEG;
  for (int j=tid; j<deg; j+=256) ssrc[j] = csrc[base+j];
  __syncthreads();
  if (tid < 64){
    float ad = a_dst2[n];
    float m = -1e30f;
    for (int j=tid; j<deg; j+=64){
      float a = a_src2[ssrc[j]] + ad;
      a = (a>0.f) ? a : NEG*a;
      sw[j] = a; m = fmaxf(m, a);
    }
    for (int off=32; off; off>>=1) m = fmaxf(m, __shfl_xor(m,off));
    float s = 0.f;
    for (int j=tid; j<deg; j+=64){ float e = __expf(sw[j]-m); sw[j]=e; s+=e; }
    for (int off=32; off; off>>=1) s += __shfl_xor(s,off);
    float inv = 1.f/(s + 1e-16f);
    for (int j=tid; j<deg; j+=64) sw[j] *= inv;
  }
  __syncthreads();
  float acc = 0.f;
  for (int j=0;j<deg;j++) acc += sw[j]*bf2f(h2b[(size_t)ssrc[j]*256 + tid]);
  out[(size_t)n*256 + tid] = acc + b2[tid];
}

extern "C" void kernel_launch(void* const* d_in, const int* in_sizes, int n_in,
                              void* d_out, int out_size, void* d_ws, size_t ws_size,
                              hipStream_t stream){
  const float* x      = (const float*)d_in[0];
  const int*   ei     = (const int*)  d_in[1];
  const float* W1     = (const float*)d_in[2];
  const float* att_s1 = (const float*)d_in[3];
  const float* att_d1 = (const float*)d_in[4];
  const float* b1     = (const float*)d_in[5];
  const float* W2     = (const float*)d_in[6];
  const float* att_s2 = (const float*)d_in[7];
  const float* att_d2 = (const float*)d_in[8];
  const float* b2     = (const float*)d_in[9];
  float* out = (float*)d_out;

  char* p = (char*)d_ws;
  auto alloc = [&](size_t bytes)->char*{ char* r = p; p += (bytes + 255) & ~(size_t)255; return r; };
  ushort* x2    = (ushort*)alloc((size_t)N_NODES*F1*2);
  ushort* W2bT  = (ushort*)alloc((size_t)F1*256*2);
  ushort* h2b   = (ushort*)alloc((size_t)N_NODES*256*2);
  float*  xagg  = (float*) alloc((size_t)N_NODES*64*4);
  float*  a_src1= (float*) alloc((size_t)N_NODES*8*4);
  float*  a_dst1= (float*) alloc((size_t)N_NODES*8*4);
  float*  a_src2= (float*) alloc((size_t)N_NODES*4);
  float*  a_dst2= (float*) alloc((size_t)N_NODES*4);
  float*  wsv   = (float*) alloc(64*4);
  float*  wdv   = (float*) alloc(64*4);
  int*    deg   = (int*)   alloc((size_t)N_NODES*4);
  int*    rowptr= (int*)   alloc((size_t)(N_NODES+1)*4);
  int*    cursor= (int*)   alloc((size_t)N_NODES*4);
  int*    csrc  = (int*)   alloc((size_t)E_TOT*4);

  hipMemsetAsync(deg,    0, (size_t)N_NODES*4, stream);
  hipMemsetAsync(a_src2, 0, (size_t)N_NODES*4, stream);
  hipMemsetAsync(a_dst2, 0, (size_t)N_NODES*4, stream);
  k_count  <<<(E_TOT+255)/256, 256, 0, stream>>>(ei, deg);
  k_scan   <<<1, 1024, 0, stream>>>(deg, rowptr, cursor);
  k_scatter<<<(E_TOT+255)/256, 256, 0, stream>>>(ei, cursor, csrc);
  k_prep   <<<1, 256, 0, stream>>>(W1, att_s1, att_d1, wsv, wdv);
  k_dots1  <<<(N_NODES+31)/32, 256, 0, stream>>>(x, wsv, wdv, a_src1, a_dst1);
  k_wT     <<<F1/64, 256, 0, stream>>>(W2, W2bT);
  k_soft1  <<<N_NODES, 64, 0, stream>>>(rowptr, csrc, a_src1, a_dst1, x, xagg);
  k_apply1 <<<N_NODES/NAPP, 256, 0, stream>>>(xagg, W1, b1, x2);
  k_gemm2m <<<(N_NODES+31)/32, 256, 0, stream>>>(x2, W2bT, h2b, att_s2, att_d2, a_src2, a_dst2);
  k_agg2   <<<N_NODES, 256, 0, stream>>>(rowptr, csrc, a_src2, a_dst2, h2b, b2, out);
}

// Round 5
// 221.562 us; speedup vs baseline: 2.7619x; 1.0481x over previous
//
#include <hip/hip_runtime.h>
#include <hip/hip_bf16.h>

#define N_NODES 20000
#define E_ORIG  160000
#define E_TOT   180000
#define HEADS   8
#define HID     256
#define F1      2048   // HEADS*HID
#define NEG     0.2f
#define MAXDEG  96
#define NAPP    32
#define GBKS    32     // K steps for gemm2: 2048/64

typedef __attribute__((ext_vector_type(8))) short  short8;
typedef __attribute__((ext_vector_type(4))) float  f32x4;

__device__ inline float bf2f(ushort u){ union{unsigned u32; float f;} v; v.u32=((unsigned)u)<<16; return v.f; }
__device__ inline ushort f2bf(float f){
  union{float f; unsigned u;} v; v.f=f;
  unsigned lsb=(v.u>>16)&1u; v.u += 0x7fffu + lsb; return (ushort)(v.u>>16);
}

__device__ inline void gload16(const ushort* g, ushort* s){
  __builtin_amdgcn_global_load_lds((const __attribute__((address_space(1))) unsigned int*)g,
                                   (__attribute__((address_space(3))) unsigned int*)s, 16, 0, 0);
}

// ---------------- CSR build ----------------
__global__ void k_count(const int* __restrict__ ei, int* __restrict__ deg){
  int e = blockIdx.x*256 + threadIdx.x;
  if (e >= E_TOT) return;
  int d = (e < E_ORIG) ? ei[E_ORIG + e] : (e - E_ORIG);
  atomicAdd(&deg[d], 1);
}

__global__ __launch_bounds__(1024) void k_scan(const int* __restrict__ deg,
                                               int* __restrict__ rowptr,
                                               int* __restrict__ cursor){
  __shared__ int s[1024];
  __shared__ int base;
  int tid = threadIdx.x;
  if (tid==0) base = 0;
  __syncthreads();
  for (int start=0; start<N_NODES; start+=1024){
    int i = start + tid;
    int v = (i<N_NODES) ? deg[i] : 0;
    s[tid] = v; __syncthreads();
    for (int off=1; off<1024; off<<=1){
      int t = (tid>=off) ? s[tid-off] : 0;
      __syncthreads();
      s[tid] += t;
      __syncthreads();
    }
    if (i<N_NODES){ int ex = base + s[tid] - v; rowptr[i]=ex; cursor[i]=ex; }
    __syncthreads();
    if (tid==0) base += s[1023];
    __syncthreads();
  }
  if (tid==0) rowptr[N_NODES] = base;
}

__global__ void k_scatter(const int* __restrict__ ei, int* __restrict__ cursor,
                          int* __restrict__ csrc){
  int e = blockIdx.x*256 + threadIdx.x;
  if (e >= E_TOT) return;
  int s, d;
  if (e < E_ORIG){ s = ei[e]; d = ei[E_ORIG + e]; }
  else           { s = d = e - E_ORIG; }
  int pos = atomicAdd(&cursor[d], 1);
  csrc[pos] = s;
}

// ---------------- factorized attention-dot weights ----------------
__global__ __launch_bounds__(256) void k_prep(const float* __restrict__ W1,
    const float* __restrict__ as1, const float* __restrict__ ad1,
    float* __restrict__ wsv, float* __restrict__ wdv){
  int tid = threadIdx.x;
  int lane = tid&63, wv = tid>>6;
  for (int kk=wv; kk<8; kk+=4){
    for (int i=0;i<7;i++){
      float v1=0.f, v2=0.f;
      for (int c=lane;c<256;c+=64){
        float w = W1[i*F1 + kk*256 + c];
        v1 += w*as1[kk*256+c];
        v2 += w*ad1[kk*256+c];
      }
      for (int off=32;off;off>>=1){ v1+=__shfl_down(v1,off); v2+=__shfl_down(v2,off); }
      if (!lane){ wsv[kk*8+i]=v1; wdv[kk*8+i]=v2; }
    }
    if (!lane){ wsv[kk*8+7]=0.f; wdv[kk*8+7]=0.f; }
  }
}

// ---------------- per-node attention logits ----------------
__global__ __launch_bounds__(256) void k_dots1(const float* __restrict__ x,
    const float* __restrict__ wsv, const float* __restrict__ wdv,
    float* __restrict__ a_src1, float* __restrict__ a_dst1){
  __shared__ float s_ws[64], s_wd[64];
  int tid = threadIdx.x;
  if (tid < 64){ s_ws[tid]=wsv[tid]; s_wd[tid]=wdv[tid]; }
  __syncthreads();
  int nl = tid>>3, k = tid&7;
  int n = blockIdx.x*32 + nl;
  if (n < N_NODES){
    float s=0.f, d=0.f;
#pragma unroll
    for (int i=0;i<7;i++){
      float xv = x[n*7+i];
      s += xv*s_ws[k*8+i]; d += xv*s_wd[k*8+i];
    }
    a_src1[n*8+k]=s; a_dst1[n*8+k]=d;
  }
}

// ---------------- W2 -> bf16 transposed [256][2048] ----------------
__global__ __launch_bounds__(256) void k_wT(const float* __restrict__ W2, ushort* __restrict__ BT){
  __shared__ ushort sh[256][65];
  int k0 = blockIdx.x*64, t = threadIdx.x;
  for (int kk=0; kk<64; kk++) sh[t][kk] = f2bf(W2[(size_t)(k0+kk)*256 + t]);
  __syncthreads();
#pragma unroll
  for (int c8=0; c8<8; c8++){
    short8 v;
#pragma unroll
    for (int j=0;j<8;j++) v[j] = (short)sh[t][c8*8+j];
    *(short8*)&BT[(size_t)t*F1 + k0 + c8*8] = v;
  }
}

// ---------------- conv1 softmax + 7-dim aggregation: one wave per node ----------------
__global__ __launch_bounds__(64) void k_soft1(const int* __restrict__ rowptr, const int* __restrict__ csrc,
    const float* __restrict__ a_src1, const float* __restrict__ a_dst1,
    const float* __restrict__ x, float* __restrict__ xagg){
  int n = blockIdx.x, lane = threadIdx.x;
  __shared__ float lw[MAXDEG][8];
  __shared__ float lx[MAXDEG][8];
  int base = rowptr[n];
  int deg  = rowptr[n+1]-base; if (deg>MAXDEG) deg=MAXDEG;
  f32x4 ad0 = *(const f32x4*)(a_dst1 + n*8);
  f32x4 ad1 = *(const f32x4*)(a_dst1 + n*8 + 4);
  float l[2][8], xv[2][7];
  bool valid[2];
#pragma unroll
  for (int t=0;t<2;t++){
    int j = lane + 64*t;
    bool v = j<deg; valid[t]=v;
    int src = v ? csrc[base+j] : 0;
    f32x4 s0, s1;
    if (v){ s0 = *(const f32x4*)(a_src1+(size_t)src*8); s1 = *(const f32x4*)(a_src1+(size_t)src*8+4); }
    else  { s0 = f32x4{0,0,0,0}; s1 = f32x4{0,0,0,0}; }
#pragma unroll
    for (int k=0;k<4;k++){
      float a = s0[k]+ad0[k]; a=(a>0.f)?a:NEG*a; l[t][k]   = v?a:-1e30f;
      float b = s1[k]+ad1[k]; b=(b>0.f)?b:NEG*b; l[t][4+k] = v?b:-1e30f;
    }
#pragma unroll
    for (int i=0;i<7;i++) xv[t][i] = v ? x[(size_t)src*7+i] : 0.f;
  }
  float m[8], sinv[8];
#pragma unroll
  for (int k=0;k<8;k++){
    float mm = fmaxf(l[0][k], l[1][k]);
    for (int off=32; off; off>>=1) mm = fmaxf(mm, __shfl_xor(mm,off));
    m[k]=mm;
  }
  float e[2][8];
#pragma unroll
  for (int k=0;k<8;k++){
    e[0][k] = valid[0]?__expf(l[0][k]-m[k]):0.f;
    e[1][k] = valid[1]?__expf(l[1][k]-m[k]):0.f;
    float ss = e[0][k]+e[1][k];
    for (int off=32; off; off>>=1) ss += __shfl_xor(ss,off);
    sinv[k] = 1.f/(ss+1e-16f);
  }
#pragma unroll
  for (int t=0;t<2;t++){
    int j = lane+64*t;
    if (j<deg){
#pragma unroll
      for (int k=0;k<8;k++) lw[j][k] = e[t][k]*sinv[k];
#pragma unroll
      for (int i=0;i<7;i++) lx[j][i] = xv[t][i];
    }
  }
  __syncthreads();
  int kk = lane>>3, i = lane&7;
  float acc = 0.f;
  if (i<7){
    for (int j=0;j<deg;j++) acc += lw[j][kk]*lx[j][i];
  }
  xagg[(size_t)n*64 + lane] = acc;
}

// ---------------- conv1 apply: x2 = ELU(xagg @ W1 + b1), bf16 ----------------
__global__ __launch_bounds__(256) void k_apply1(const float* __restrict__ xagg,
    const float* __restrict__ W1, const float* __restrict__ b1, ushort* __restrict__ x2){
  int tid = threadIdx.x;
  int k = tid>>5, c0 = (tid&31)<<3;
  f32x4 w1a[7], w1b[7];
#pragma unroll
  for (int i=0;i<7;i++){
    const float* p = W1 + i*F1 + (k<<8) + c0;
    w1a[i] = *(const f32x4*)p; w1b[i] = *(const f32x4*)(p+4);
  }
  f32x4 b1a = *(const f32x4*)(b1 + (k<<8)+c0);
  f32x4 b1b = *(const f32x4*)(b1 + (k<<8)+c0+4);

  __shared__ float sxa[NAPP*64];
  int nb = blockIdx.x*NAPP;
  for (int idx=tid; idx<NAPP*64; idx+=256)
    sxa[idx] = xagg[(size_t)nb*64 + idx];
  __syncthreads();
#pragma unroll 4
  for (int g=0; g<NAPP; g++){
    int n = nb+g;
    const float* xa = &sxa[g*64 + (k<<3)];
    f32x4 ha=b1a, hb=b1b;
#pragma unroll
    for (int i=0;i<7;i++){
      float xv = xa[i];
      ha += xv*w1a[i]; hb += xv*w1b[i];
    }
    short8 o;
#pragma unroll
    for (int j=0;j<4;j++){ float v=ha[j]; v=(v>0.f)?v:(__expf(v)-1.f); o[j]  =(short)f2bf(v); }
#pragma unroll
    for (int j=0;j<4;j++){ float v=hb[j]; v=(v>0.f)?v:(__expf(v)-1.f); o[4+j]=(short)f2bf(v); }
    *(short8*)(x2 + (size_t)n*F1 + (k<<8) + c0) = o;
  }
}

// ---------------- conv2 GEMM: MFMA bf16, BM=64 BN=256 BK=64, 8 waves, 2-phase dbuf ----------------
// LDS: 2 buffers x (A 64x64 + B 256x64) bf16 = 80 KB -> 2 blocks/CU.
// Per K-step: issue next-tile stage (5 gload16/thread), ds_read + 16 MFMA on current,
// ONE __syncthreads() (drains the prefetch, after ~200cy of compute cover).
__global__ __launch_bounds__(512,4) void k_gemm2m(const ushort* __restrict__ A,
    const ushort* __restrict__ BT, ushort* __restrict__ h2b,
    const float* __restrict__ as2, const float* __restrict__ ad2,
    float* __restrict__ a_src2, float* __restrict__ a_dst2){
  __shared__ __align__(16) ushort S[2][(64+256)*64];   // [buf][A:4096 | B:16384]
  int tid = threadIdx.x;
  int m0 = blockIdx.x*64;
  int w = tid>>6, l = tid&63;
  int lrow = l&15, lk = l>>4;
  int mr = (w&1)*32, nc = (w>>1)*64;   // wave's 32x64 sub-tile

  // 2560 staging loads = 5 per thread; linear LDS dest, inverse-swizzled global src
  const ushort* gp[5];
  int dof[5];
#pragma unroll
  for (int rep=0;rep<5;rep++){
    int lin = rep*512 + tid;
    if (lin < 512){                    // A region: row r, slot s
      int r = lin>>3, s = lin&7;
      int grow = m0 + r; if (grow >= N_NODES) grow = N_NODES-1;
      gp[rep] = A + (size_t)grow*F1 + ((s ^ (r&7))<<3);
    } else {                           // B region: col c, slot s
      int j = lin - 512;
      int c = j>>3, s = j&7;
      gp[rep] = BT + (size_t)c*F1 + ((s ^ (c&7))<<3);
    }
    dof[rep] = lin<<3;
  }

  f32x4 acc[2][4] = {};

  // prologue: stage tile 0
#pragma unroll
  for (int rep=0;rep<5;rep++) gload16(gp[rep], &S[0][dof[rep]]);
  __syncthreads();

  int cur = 0;
  for (int t=0; t<GBKS; t++){
    if (t+1 < GBKS){
      int k0 = (t+1)<<6;
#pragma unroll
      for (int rep=0;rep<5;rep++) gload16(gp[rep]+k0, &S[cur^1][dof[rep]]);
    }
    const ushort* as_ = &S[cur][0];
    const ushort* bs_ = &S[cur][4096];
    short8 af[2][2], bfr[4][2];
#pragma unroll
    for (int m=0;m<2;m++){
      int r = mr + (m<<4) + lrow;
#pragma unroll
      for (int kk=0;kk<2;kk++)
        af[m][kk] = *(const short8*)&as_[(r<<6) + ((((kk<<2)|lk) ^ (r&7))<<3)];
    }
#pragma unroll
    for (int n=0;n<4;n++){
      int c = nc + (n<<4) + lrow;
#pragma unroll
      for (int kk=0;kk<2;kk++)
        bfr[n][kk] = *(const short8*)&bs_[(c<<6) + ((((kk<<2)|lk) ^ (c&7))<<3)];
    }
#pragma unroll
    for (int kk=0;kk<2;kk++)
#pragma unroll
      for (int m=0;m<2;m++)
#pragma unroll
        for (int n=0;n<4;n++)
          acc[m][n] = __builtin_amdgcn_mfma_f32_16x16x32_bf16(af[m][kk], bfr[n][kk], acc[m][n], 0,0,0);
    __syncthreads();
    cur ^= 1;
  }

  // epilogue: bf16 h2 store + fused attention dots
  float s2v[4], d2v[4];
#pragma unroll
  for (int n=0;n<4;n++){
    int col = nc + (n<<4) + lrow;
    s2v[n]=as2[col]; d2v[n]=ad2[col];
  }
#pragma unroll
  for (int m=0;m<2;m++){
#pragma unroll
    for (int j=0;j<4;j++){
      int grow = m0 + mr + (m<<4) + (lk<<2) + j;
      bool ok = grow < N_NODES;
      float ps=0.f, pd=0.f;
#pragma unroll
      for (int n=0;n<4;n++){
        float v = acc[m][n][j];
        ps += v*s2v[n]; pd += v*d2v[n];
        if (ok) h2b[(size_t)grow*256 + nc+(n<<4)+lrow] = f2bf(v);
      }
      ps += __shfl_xor(ps,8); ps += __shfl_xor(ps,4); ps += __shfl_xor(ps,2); ps += __shfl_xor(ps,1);
      pd += __shfl_xor(pd,8); pd += __shfl_xor(pd,4); pd += __shfl_xor(pd,2); pd += __shfl_xor(pd,1);
      if (ok && lrow==0){
        atomicAdd(&a_src2[grow], ps);
        atomicAdd(&a_dst2[grow], pd);
      }
    }
  }
}

// ---------------- conv2 aggregation → output ----------------
__global__ __launch_bounds__(256) void k_agg2(const int* __restrict__ rowptr, const int* __restrict__ csrc,
    const float* __restrict__ a_src2, const float* __restrict__ a_dst2, const ushort* __restrict__ h2b,
    const float* __restrict__ b2, float* __restrict__ out){
  int n = blockIdx.x, tid = threadIdx.x;
  __shared__ int   ssrc[MAXDEG];
  __shared__ float sw[MAXDEG];
  int base = rowptr[n];
  int deg  = rowptr[n+1] - base;
  if (deg > MAXDEG) deg = MAXDEG;
  for (int j=tid; j<deg; j+=256) ssrc[j] = csrc[base+j];
  __syncthreads();
  if (tid < 64){
    float ad = a_dst2[n];
    float m = -1e30f;
    for (int j=tid; j<deg; j+=64){
      float a = a_src2[ssrc[j]] + ad;
      a = (a>0.f) ? a : NEG*a;
      sw[j] = a; m = fmaxf(m, a);
    }
    for (int off=32; off; off>>=1) m = fmaxf(m, __shfl_xor(m,off));
    float s = 0.f;
    for (int j=tid; j<deg; j+=64){ float e = __expf(sw[j]-m); sw[j]=e; s+=e; }
    for (int off=32; off; off>>=1) s += __shfl_xor(s,off);
    float inv = 1.f/(s + 1e-16f);
    for (int j=tid; j<deg; j+=64) sw[j] *= inv;
  }
  __syncthreads();
  float acc = 0.f;
  for (int j=0;j<deg;j++) acc += sw[j]*bf2f(h2b[(size_t)ssrc[j]*256 + tid]);
  out[(size_t)n*256 + tid] = acc + b2[tid];
}

extern "C" void kernel_launch(void* const* d_in, const int* in_sizes, int n_in,
                              void* d_out, int out_size, void* d_ws, size_t ws_size,
                              hipStream_t stream){
  const float* x      = (const float*)d_in[0];
  const int*   ei     = (const int*)  d_in[1];
  const float* W1     = (const float*)d_in[2];
  const float* att_s1 = (const float*)d_in[3];
  const float* att_d1 = (const float*)d_in[4];
  const float* b1     = (const float*)d_in[5];
  const float* W2     = (const float*)d_in[6];
  const float* att_s2 = (const float*)d_in[7];
  const float* att_d2 = (const float*)d_in[8];
  const float* b2     = (const float*)d_in[9];
  float* out = (float*)d_out;

  char* p = (char*)d_ws;
  auto alloc = [&](size_t bytes)->char*{ char* r = p; p += (bytes + 255) & ~(size_t)255; return r; };
  ushort* x2    = (ushort*)alloc((size_t)N_NODES*F1*2);
  ushort* W2bT  = (ushort*)alloc((size_t)F1*256*2);
  ushort* h2b   = (ushort*)alloc((size_t)N_NODES*256*2);
  float*  xagg  = (float*) alloc((size_t)N_NODES*64*4);
  float*  a_src1= (float*) alloc((size_t)N_NODES*8*4);
  float*  a_dst1= (float*) alloc((size_t)N_NODES*8*4);
  float*  a_src2= (float*) alloc((size_t)N_NODES*4);
  float*  a_dst2= (float*) alloc((size_t)N_NODES*4);
  float*  wsv   = (float*) alloc(64*4);
  float*  wdv   = (float*) alloc(64*4);
  int*    deg   = (int*)   alloc((size_t)N_NODES*4);
  int*    rowptr= (int*)   alloc((size_t)(N_NODES+1)*4);
  int*    cursor= (int*)   alloc((size_t)N_NODES*4);
  int*    csrc  = (int*)   alloc((size_t)E_TOT*4);

  hipMemsetAsync(deg,    0, (size_t)N_NODES*4, stream);
  hipMemsetAsync(a_src2, 0, (size_t)N_NODES*4, stream);
  hipMemsetAsync(a_dst2, 0, (size_t)N_NODES*4, stream);
  k_count  <<<(E_TOT+255)/256, 256, 0, stream>>>(ei, deg);
  k_scan   <<<1, 1024, 0, stream>>>(deg, rowptr, cursor);
  k_scatter<<<(E_TOT+255)/256, 256, 0, stream>>>(ei, cursor, csrc);
  k_prep   <<<1, 256, 0, stream>>>(W1, att_s1, att_d1, wsv, wdv);
  k_dots1  <<<(N_NODES+31)/32, 256, 0, stream>>>(x, wsv, wdv, a_src1, a_dst1);
  k_wT     <<<F1/64, 256, 0, stream>>>(W2, W2bT);
  k_soft1  <<<N_NODES, 64, 0, stream>>>(rowptr, csrc, a_src1, a_dst1, x, xagg);
  k_apply1 <<<N_NODES/NAPP, 256, 0, stream>>>(xagg, W1, b1, x2);
  k_gemm2m <<<(N_NODES+63)/64, 512, 0, stream>>>(x2, W2bT, h2b, att_s2, att_d2, a_src2, a_dst2);
  k_agg2   <<<N_NODES, 256, 0, stream>>>(rowptr, csrc, a_src2, a_dst2, h2b, b2, out);
}

// Round 6
// 202.866 us; speedup vs baseline: 3.0165x; 1.0922x over previous
//
#include <hip/hip_runtime.h>
#include <hip/hip_bf16.h>

#define N_NODES 20000
#define E_ORIG  160000
#define E_TOT   180000
#define HEADS   8
#define HID     256
#define F1      2048   // HEADS*HID
#define NEG     0.2f
#define MAXDEG  96
#define NAPP    32
#define GBKS    32     // K steps for gemm2: 2048/64
#define SCAN_PER 20

typedef __attribute__((ext_vector_type(8))) short  short8;
typedef __attribute__((ext_vector_type(4))) float  f32x4;

__device__ inline float bf2f(ushort u){ union{unsigned u32; float f;} v; v.u32=((unsigned)u)<<16; return v.f; }
__device__ inline ushort f2bf(float f){
  union{float f; unsigned u;} v; v.f=f;
  unsigned lsb=(v.u>>16)&1u; v.u += 0x7fffu + lsb; return (ushort)(v.u>>16);
}

__device__ inline void gload16(const ushort* g, ushort* s){
  __builtin_amdgcn_global_load_lds((const __attribute__((address_space(1))) unsigned int*)g,
                                   (__attribute__((address_space(3))) unsigned int*)s, 16, 0, 0);
}

// ---------------- zero deg (replaces pathological 44us hipMemsetAsync fill) ----------------
__global__ void k_zero(int* __restrict__ deg){
  int i = blockIdx.x*256 + threadIdx.x;
  if (i < N_NODES) deg[i] = 0;
}

// ---------------- CSR build ----------------
__global__ void k_count(const int* __restrict__ ei, int* __restrict__ deg){
  int e = blockIdx.x*256 + threadIdx.x;
  if (e >= E_TOT) return;
  int d = (e < E_ORIG) ? ei[E_ORIG + e] : (e - E_ORIG);
  atomicAdd(&deg[d], 1);
}

// two-level scan: 2 barriers total (was ~200)
__global__ __launch_bounds__(1024) void k_scan(const int* __restrict__ deg,
                                               int* __restrict__ rowptr,
                                               int* __restrict__ cursor){
  __shared__ int swv[16];
  int t = threadIdx.x;
  int i0 = t*SCAN_PER;
  int loc[SCAN_PER]; int s = 0;
#pragma unroll
  for (int i=0;i<SCAN_PER;i++){
    int idx = i0+i;
    int d = (idx<N_NODES) ? deg[idx] : 0;
    loc[i] = s; s += d;
  }
  int lane = t&63, wv = t>>6;
  int incl = s;
  for (int off=1; off<64; off<<=1){
    int u = __shfl_up(incl, off);
    if (lane>=off) incl += u;
  }
  if (lane==63) swv[wv] = incl;
  __syncthreads();
  if (t==0){
    int a = 0;
    for (int k=0;k<16;k++){ int x = swv[k]; swv[k] = a; a += x; }
  }
  __syncthreads();
  int base = swv[wv] + incl - s;
#pragma unroll
  for (int i=0;i<SCAN_PER;i++){
    int idx = i0+i;
    if (idx<N_NODES){ int ex = base+loc[i]; rowptr[idx]=ex; cursor[idx]=ex; }
  }
  if (t==1023) rowptr[N_NODES] = base + s;
}

__global__ void k_scatter(const int* __restrict__ ei, int* __restrict__ cursor,
                          int* __restrict__ csrc){
  int e = blockIdx.x*256 + threadIdx.x;
  if (e >= E_TOT) return;
  int s, d;
  if (e < E_ORIG){ s = ei[e]; d = ei[E_ORIG + e]; }
  else           { s = d = e - E_ORIG; }
  int pos = atomicAdd(&cursor[d], 1);
  csrc[pos] = s;
}

// ---------------- factorized attention-dot weights ----------------
__global__ __launch_bounds__(256) void k_prep(const float* __restrict__ W1,
    const float* __restrict__ as1, const float* __restrict__ ad1,
    float* __restrict__ wsv, float* __restrict__ wdv){
  int tid = threadIdx.x;
  int lane = tid&63, wv = tid>>6;
  for (int kk=wv; kk<8; kk+=4){
    for (int i=0;i<7;i++){
      float v1=0.f, v2=0.f;
      for (int c=lane;c<256;c+=64){
        float w = W1[i*F1 + kk*256 + c];
        v1 += w*as1[kk*256+c];
        v2 += w*ad1[kk*256+c];
      }
      for (int off=32;off;off>>=1){ v1+=__shfl_down(v1,off); v2+=__shfl_down(v2,off); }
      if (!lane){ wsv[kk*8+i]=v1; wdv[kk*8+i]=v2; }
    }
    if (!lane){ wsv[kk*8+7]=0.f; wdv[kk*8+7]=0.f; }
  }
}

// ---------------- per-node attention logits ----------------
__global__ __launch_bounds__(256) void k_dots1(const float* __restrict__ x,
    const float* __restrict__ wsv, const float* __restrict__ wdv,
    float* __restrict__ a_src1, float* __restrict__ a_dst1){
  __shared__ float s_ws[64], s_wd[64];
  int tid = threadIdx.x;
  if (tid < 64){ s_ws[tid]=wsv[tid]; s_wd[tid]=wdv[tid]; }
  __syncthreads();
  int nl = tid>>3, k = tid&7;
  int n = blockIdx.x*32 + nl;
  if (n < N_NODES){
    float s=0.f, d=0.f;
#pragma unroll
    for (int i=0;i<7;i++){
      float xv = x[n*7+i];
      s += xv*s_ws[k*8+i]; d += xv*s_wd[k*8+i];
    }
    a_src1[n*8+k]=s; a_dst1[n*8+k]=d;
  }
}

// ---------------- W2 -> bf16 transposed [256][2048] ----------------
__global__ __launch_bounds__(256) void k_wT(const float* __restrict__ W2, ushort* __restrict__ BT){
  __shared__ ushort sh[256][65];
  int k0 = blockIdx.x*64, t = threadIdx.x;
  for (int kk=0; kk<64; kk++) sh[t][kk] = f2bf(W2[(size_t)(k0+kk)*256 + t]);
  __syncthreads();
#pragma unroll
  for (int c8=0; c8<8; c8++){
    short8 v;
#pragma unroll
    for (int j=0;j<8;j++) v[j] = (short)sh[t][c8*8+j];
    *(short8*)&BT[(size_t)t*F1 + k0 + c8*8] = v;
  }
}

// ---------------- conv1 softmax + 7-dim aggregation: one wave per node ----------------
__global__ __launch_bounds__(64) void k_soft1(const int* __restrict__ rowptr, const int* __restrict__ csrc,
    const float* __restrict__ a_src1, const float* __restrict__ a_dst1,
    const float* __restrict__ x, float* __restrict__ xagg){
  int n = blockIdx.x, lane = threadIdx.x;
  __shared__ float lw[MAXDEG][8];
  __shared__ float lx[MAXDEG][8];
  int base = rowptr[n];
  int deg  = rowptr[n+1]-base; if (deg>MAXDEG) deg=MAXDEG;
  f32x4 ad0 = *(const f32x4*)(a_dst1 + n*8);
  f32x4 ad1 = *(const f32x4*)(a_dst1 + n*8 + 4);
  float l[2][8], xv[2][7];
  bool valid[2];
#pragma unroll
  for (int t=0;t<2;t++){
    int j = lane + 64*t;
    bool v = j<deg; valid[t]=v;
    int src = v ? csrc[base+j] : 0;
    f32x4 s0, s1;
    if (v){ s0 = *(const f32x4*)(a_src1+(size_t)src*8); s1 = *(const f32x4*)(a_src1+(size_t)src*8+4); }
    else  { s0 = f32x4{0,0,0,0}; s1 = f32x4{0,0,0,0}; }
#pragma unroll
    for (int k=0;k<4;k++){
      float a = s0[k]+ad0[k]; a=(a>0.f)?a:NEG*a; l[t][k]   = v?a:-1e30f;
      float b = s1[k]+ad1[k]; b=(b>0.f)?b:NEG*b; l[t][4+k] = v?b:-1e30f;
    }
#pragma unroll
    for (int i=0;i<7;i++) xv[t][i] = v ? x[(size_t)src*7+i] : 0.f;
  }
  float m[8], sinv[8];
#pragma unroll
  for (int k=0;k<8;k++){
    float mm = fmaxf(l[0][k], l[1][k]);
    for (int off=32; off; off>>=1) mm = fmaxf(mm, __shfl_xor(mm,off));
    m[k]=mm;
  }
  float e[2][8];
#pragma unroll
  for (int k=0;k<8;k++){
    e[0][k] = valid[0]?__expf(l[0][k]-m[k]):0.f;
    e[1][k] = valid[1]?__expf(l[1][k]-m[k]):0.f;
    float ss = e[0][k]+e[1][k];
    for (int off=32; off; off>>=1) ss += __shfl_xor(ss,off);
    sinv[k] = 1.f/(ss+1e-16f);
  }
#pragma unroll
  for (int t=0;t<2;t++){
    int j = lane+64*t;
    if (j<deg){
#pragma unroll
      for (int k=0;k<8;k++) lw[j][k] = e[t][k]*sinv[k];
#pragma unroll
      for (int i=0;i<7;i++) lx[j][i] = xv[t][i];
    }
  }
  __syncthreads();
  int kk = lane>>3, i = lane&7;
  float acc = 0.f;
  if (i<7){
    for (int j=0;j<deg;j++) acc += lw[j][kk]*lx[j][i];
  }
  xagg[(size_t)n*64 + lane] = acc;
}

// ---------------- conv1 apply: x2 = ELU(xagg @ W1 + b1), bf16 ----------------
__global__ __launch_bounds__(256) void k_apply1(const float* __restrict__ xagg,
    const float* __restrict__ W1, const float* __restrict__ b1, ushort* __restrict__ x2){
  int tid = threadIdx.x;
  int k = tid>>5, c0 = (tid&31)<<3;
  f32x4 w1a[7], w1b[7];
#pragma unroll
  for (int i=0;i<7;i++){
    const float* p = W1 + i*F1 + (k<<8) + c0;
    w1a[i] = *(const f32x4*)p; w1b[i] = *(const f32x4*)(p+4);
  }
  f32x4 b1a = *(const f32x4*)(b1 + (k<<8)+c0);
  f32x4 b1b = *(const f32x4*)(b1 + (k<<8)+c0+4);

  __shared__ float sxa[NAPP*64];
  int nb = blockIdx.x*NAPP;
  for (int idx=tid; idx<NAPP*64; idx+=256)
    sxa[idx] = xagg[(size_t)nb*64 + idx];
  __syncthreads();
#pragma unroll 4
  for (int g=0; g<NAPP; g++){
    int n = nb+g;
    const float* xa = &sxa[g*64 + (k<<3)];
    f32x4 ha=b1a, hb=b1b;
#pragma unroll
    for (int i=0;i<7;i++){
      float xv = xa[i];
      ha += xv*w1a[i]; hb += xv*w1b[i];
    }
    short8 o;
#pragma unroll
    for (int j=0;j<4;j++){ float v=ha[j]; v=(v>0.f)?v:(__expf(v)-1.f); o[j]  =(short)f2bf(v); }
#pragma unroll
    for (int j=0;j<4;j++){ float v=hb[j]; v=(v>0.f)?v:(__expf(v)-1.f); o[4+j]=(short)f2bf(v); }
    *(short8*)(x2 + (size_t)n*F1 + (k<<8) + c0) = o;
  }
}

// ---------------- conv2 GEMM: MFMA bf16, BM=64 BN=256 BK=64, 8 waves, 2-phase dbuf ----------------
// Epilogue: attention dots reduced across waves via LDS (reusing staging buffer) -> clean
// per-node stores, no global atomics, no pre-zeroing of a_src2/a_dst2.
__global__ __launch_bounds__(512,4) void k_gemm2m(const ushort* __restrict__ A,
    const ushort* __restrict__ BT, ushort* __restrict__ h2b,
    const float* __restrict__ as2, const float* __restrict__ ad2,
    float* __restrict__ a_src2, float* __restrict__ a_dst2){
  __shared__ __align__(16) ushort S[2][(64+256)*64];   // [buf][A:4096 | B:16384]
  int tid = threadIdx.x;
  int m0 = blockIdx.x*64;
  int w = tid>>6, l = tid&63;
  int lrow = l&15, lk = l>>4;
  int mr = (w&1)*32, nc = (w>>1)*64;   // wave's 32x64 sub-tile

  const ushort* gp[5];
  int dof[5];
#pragma unroll
  for (int rep=0;rep<5;rep++){
    int lin = rep*512 + tid;
    if (lin < 512){                    // A region
      int r = lin>>3, s = lin&7;
      int grow = m0 + r; if (grow >= N_NODES) grow = N_NODES-1;
      gp[rep] = A + (size_t)grow*F1 + ((s ^ (r&7))<<3);
    } else {                           // B region
      int j = lin - 512;
      int c = j>>3, s = j&7;
      gp[rep] = BT + (size_t)c*F1 + ((s ^ (c&7))<<3);
    }
    dof[rep] = lin<<3;
  }

  f32x4 acc[2][4] = {};

#pragma unroll
  for (int rep=0;rep<5;rep++) gload16(gp[rep], &S[0][dof[rep]]);
  __syncthreads();

  int cur = 0;
  for (int t=0; t<GBKS; t++){
    if (t+1 < GBKS){
      int k0 = (t+1)<<6;
#pragma unroll
      for (int rep=0;rep<5;rep++) gload16(gp[rep]+k0, &S[cur^1][dof[rep]]);
    }
    const ushort* as_ = &S[cur][0];
    const ushort* bs_ = &S[cur][4096];
    short8 af[2][2], bfr[4][2];
#pragma unroll
    for (int m=0;m<2;m++){
      int r = mr + (m<<4) + lrow;
#pragma unroll
      for (int kk=0;kk<2;kk++)
        af[m][kk] = *(const short8*)&as_[(r<<6) + ((((kk<<2)|lk) ^ (r&7))<<3)];
    }
#pragma unroll
    for (int n=0;n<4;n++){
      int c = nc + (n<<4) + lrow;
#pragma unroll
      for (int kk=0;kk<2;kk++)
        bfr[n][kk] = *(const short8*)&bs_[(c<<6) + ((((kk<<2)|lk) ^ (c&7))<<3)];
    }
#pragma unroll
    for (int kk=0;kk<2;kk++)
#pragma unroll
      for (int m=0;m<2;m++)
#pragma unroll
        for (int n=0;n<4;n++)
          acc[m][n] = __builtin_amdgcn_mfma_f32_16x16x32_bf16(af[m][kk], bfr[n][kk], acc[m][n], 0,0,0);
    __syncthreads();
    cur ^= 1;
  }

  // epilogue: bf16 h2 store + attention-dot partials into reused LDS
  float* sps = (float*)&S[0][0];       // [64 rows][4 chunks]
  float* spd = sps + 256;
  float s2v[4], d2v[4];
#pragma unroll
  for (int n=0;n<4;n++){
    int col = nc + (n<<4) + lrow;
    s2v[n]=as2[col]; d2v[n]=ad2[col];
  }
#pragma unroll
  for (int m=0;m<2;m++){
#pragma unroll
    for (int j=0;j<4;j++){
      int lrow64 = mr + (m<<4) + (lk<<2) + j;   // row within the 64-row tile
      int grow = m0 + lrow64;
      bool ok = grow < N_NODES;
      float ps=0.f, pd=0.f;
#pragma unroll
      for (int n=0;n<4;n++){
        float v = acc[m][n][j];
        ps += v*s2v[n]; pd += v*d2v[n];
        if (ok) h2b[(size_t)grow*256 + nc+(n<<4)+lrow] = f2bf(v);
      }
      ps += __shfl_xor(ps,8); ps += __shfl_xor(ps,4); ps += __shfl_xor(ps,2); ps += __shfl_xor(ps,1);
      pd += __shfl_xor(pd,8); pd += __shfl_xor(pd,4); pd += __shfl_xor(pd,2); pd += __shfl_xor(pd,1);
      if (lrow==0){
        sps[(lrow64<<2) | (w>>1)] = ps;
        spd[(lrow64<<2) | (w>>1)] = pd;
      }
    }
  }
  __syncthreads();
  if (tid < 64){
    int grow = m0 + tid;
    if (grow < N_NODES){
      f32x4 a = *(const f32x4*)&sps[tid<<2];
      f32x4 b = *(const f32x4*)&spd[tid<<2];
      a_src2[grow] = a[0]+a[1]+a[2]+a[3];
      a_dst2[grow] = b[0]+b[1]+b[2]+b[3];
    }
  }
}

// ---------------- conv2 aggregation → output ----------------
__global__ __launch_bounds__(256) void k_agg2(const int* __restrict__ rowptr, const int* __restrict__ csrc,
    const float* __restrict__ a_src2, const float* __restrict__ a_dst2, const ushort* __restrict__ h2b,
    const float* __restrict__ b2, float* __restrict__ out){
  int n = blockIdx.x, tid = threadIdx.x;
  __shared__ int   ssrc[MAXDEG];
  __shared__ float sw[MAXDEG];
  int base = rowptr[n];
  int deg  = rowptr[n+1] - base;
  if (deg > MAXDEG) deg = MAXDEG;
  for (int j=tid; j<deg; j+=256) ssrc[j] = csrc[base+j];
  __syncthreads();
  if (tid < 64){
    float ad = a_dst2[n];
    float m = -1e30f;
    for (int j=tid; j<deg; j+=64){
      float a = a_src2[ssrc[j]] + ad;
      a = (a>0.f) ? a : NEG*a;
      sw[j] = a; m = fmaxf(m, a);
    }
    for (int off=32; off; off>>=1) m = fmaxf(m, __shfl_xor(m,off));
    float s = 0.f;
    for (int j=tid; j<deg; j+=64){ float e = __expf(sw[j]-m); sw[j]=e; s+=e; }
    for (int off=32; off; off>>=1) s += __shfl_xor(s,off);
    float inv = 1.f/(s + 1e-16f);
    for (int j=tid; j<deg; j+=64) sw[j] *= inv;
  }
  __syncthreads();
  float acc = 0.f;
  for (int j=0;j<deg;j++) acc += sw[j]*bf2f(h2b[(size_t)ssrc[j]*256 + tid]);
  out[(size_t)n*256 + tid] = acc + b2[tid];
}

extern "C" void kernel_launch(void* const* d_in, const int* in_sizes, int n_in,
                              void* d_out, int out_size, void* d_ws, size_t ws_size,
                              hipStream_t stream){
  const float* x      = (const float*)d_in[0];
  const int*   ei     = (const int*)  d_in[1];
  const float* W1     = (const float*)d_in[2];
  const float* att_s1 = (const float*)d_in[3];
  const float* att_d1 = (const float*)d_in[4];
  const float* b1     = (const float*)d_in[5];
  const float* W2     = (const float*)d_in[6];
  const float* att_s2 = (const float*)d_in[7];
  const float* att_d2 = (const float*)d_in[8];
  const float* b2     = (const float*)d_in[9];
  float* out = (float*)d_out;

  char* p = (char*)d_ws;
  auto alloc = [&](size_t bytes)->char*{ char* r = p; p += (bytes + 255) & ~(size_t)255; return r; };
  ushort* x2    = (ushort*)alloc((size_t)N_NODES*F1*2);
  ushort* W2bT  = (ushort*)alloc((size_t)F1*256*2);
  ushort* h2b   = (ushort*)alloc((size_t)N_NODES*256*2);
  float*  xagg  = (float*) alloc((size_t)N_NODES*64*4);
  float*  a_src1= (float*) alloc((size_t)N_NODES*8*4);
  float*  a_dst1= (float*) alloc((size_t)N_NODES*8*4);
  float*  a_src2= (float*) alloc((size_t)N_NODES*4);
  float*  a_dst2= (float*) alloc((size_t)N_NODES*4);
  float*  wsv   = (float*) alloc(64*4);
  float*  wdv   = (float*) alloc(64*4);
  int*    deg   = (int*)   alloc((size_t)N_NODES*4);
  int*    rowptr= (int*)   alloc((size_t)(N_NODES+1)*4);
  int*    cursor= (int*)   alloc((size_t)N_NODES*4);
  int*    csrc  = (int*)   alloc((size_t)E_TOT*4);

  k_zero   <<<(N_NODES+255)/256, 256, 0, stream>>>(deg);
  k_count  <<<(E_TOT+255)/256, 256, 0, stream>>>(ei, deg);
  k_scan   <<<1, 1024, 0, stream>>>(deg, rowptr, cursor);
  k_scatter<<<(E_TOT+255)/256, 256, 0, stream>>>(ei, cursor, csrc);
  k_prep   <<<1, 256, 0, stream>>>(W1, att_s1, att_d1, wsv, wdv);
  k_dots1  <<<(N_NODES+31)/32, 256, 0, stream>>>(x, wsv, wdv, a_src1, a_dst1);
  k_wT     <<<F1/64, 256, 0, stream>>>(W2, W2bT);
  k_soft1  <<<N_NODES, 64, 0, stream>>>(rowptr, csrc, a_src1, a_dst1, x, xagg);
  k_apply1 <<<N_NODES/NAPP, 256, 0, stream>>>(xagg, W1, b1, x2);
  k_gemm2m <<<(N_NODES+63)/64, 512, 0, stream>>>(x2, W2bT, h2b, att_s2, att_d2, a_src2, a_dst2);
  k_agg2   <<<N_NODES, 256, 0, stream>>>(rowptr, csrc, a_src2, a_dst2, h2b, b2, out);
}